// Round 1
// baseline (616.333 us; speedup 1.0000x reference)
//
#include <hip/hip_runtime.h>
#include <math.h>

// LatentVoxelGrid: N=65536 pts, M=131072 voxels, K=8 cand, D=64.
// Stage 1: wave-per-point sim MLP + softmax + atomic scatter (msg, wsum in ws).
// Stage 2: wave-per-voxel gate MLP + GRU, weights staged/transposed in LDS.

__device__ __forceinline__ float lane_bcast(float v, int i) {
  return __int_as_float(__builtin_amdgcn_readlane(__float_as_int(v), i));
}

__device__ __forceinline__ float wave_sum(float v) {
#pragma unroll
  for (int m = 32; m >= 1; m >>= 1) v += __shfl_xor(v, m, 64);
  return v;
}

__global__ __launch_bounds__(256) void zero_ws(float* __restrict__ p, long n) {
  long i = (long)blockIdx.x * blockDim.x + threadIdx.x;
  long stride = (long)gridDim.x * blockDim.x;
  float4* p4 = (float4*)p;
  long n4 = n >> 2;
  for (long j = i; j < n4; j += stride) p4[j] = make_float4(0.f, 0.f, 0.f, 0.f);
}

__global__ __launch_bounds__(256) void stage1(
    const float* __restrict__ f_pts, const float* __restrict__ pts,
    const float* __restrict__ z_latent, const float* __restrict__ centers,
    const int* __restrict__ cand_idx,
    const float* __restrict__ sim_w1, const float* __restrict__ sim_b1,
    const float* __restrict__ sim_w2,
    float* __restrict__ msg, float* __restrict__ wsum, int npts)
{
  __shared__ float W1s[131 * 64];  // row-major (i, j): lane j reads col j, conflict-free
  __shared__ float b1s[64];
  __shared__ float w2s[64];
  int t = threadIdx.x;
  for (int s = t; s < 131 * 64; s += 256) W1s[s] = sim_w1[s];
  if (t < 64) { b1s[t] = sim_b1[t]; w2s[t] = sim_w2[t]; }
  __syncthreads();

  int lane = t & 63;
  int gwave = (blockIdx.x * 256 + t) >> 6;
  int nwaves = (gridDim.x * 256) >> 6;

  for (int n = gwave; n < npts; n += nwaves) {
    float f = f_pts[n * 64 + lane];
    float p0 = pts[n * 3 + 0], p1 = pts[n * 3 + 1], p2 = pts[n * 3 + 2];

    // candidate-invariant half of the MLP: hb[j] = b1[j] + sum_i f[i] W1[i][j]
    float hb = b1s[lane];
#pragma unroll 16
    for (int i = 0; i < 64; ++i)
      hb = fmaf(lane_bcast(f, i), W1s[i * 64 + lane], hb);

    int cidx[8];
    float sims[8];
#pragma unroll
    for (int k = 0; k < 8; ++k) {
      int vi = cand_idx[n * 8 + k];
      cidx[k] = vi;
      float z = z_latent[(long)vi * 64 + lane];
      float d0 = p0 - centers[vi * 3 + 0];
      float d1 = p1 - centers[vi * 3 + 1];
      float d2 = p2 - centers[vi * 3 + 2];
      float h = hb;
#pragma unroll 16
      for (int i = 0; i < 64; ++i)
        h = fmaf(lane_bcast(z, i), W1s[(64 + i) * 64 + lane], h);
      h = fmaf(d0, W1s[128 * 64 + lane], h);
      h = fmaf(d1, W1s[129 * 64 + lane], h);
      h = fmaf(d2, W1s[130 * 64 + lane], h);
      h = fmaxf(h, 0.0f);
      // sim_b2 is a uniform shift -> cancels in softmax, skip it
      sims[k] = wave_sum(h * w2s[lane]);
    }

    // softmax over K=8 at temperature TAU=0.3
    float mx = sims[0];
#pragma unroll
    for (int k = 1; k < 8; ++k) mx = fmaxf(mx, sims[k]);
    float e[8];
    float ssum = 0.f;
#pragma unroll
    for (int k = 0; k < 8; ++k) {
      e[k] = __expf((sims[k] - mx) * (1.0f / 0.3f));
      ssum += e[k];
    }
    float inv = 1.0f / ssum;
#pragma unroll
    for (int k = 0; k < 8; ++k) {
      float w = e[k] * inv;
      atomicAdd(&msg[(long)cidx[k] * 64 + lane], w * f);
      if (lane == 0) atomicAdd(&wsum[cidx[k]], w);
    }
  }
}

__global__ __launch_bounds__(1024) void stage2(
    const float* __restrict__ z_latent,
    const float* __restrict__ gate_w1, const float* __restrict__ gate_b1,
    const float* __restrict__ gate_w2, const float* __restrict__ gate_b2,
    const float* __restrict__ W_ih, const float* __restrict__ W_hh,
    const float* __restrict__ b_ih, const float* __restrict__ b_hh,
    const float* __restrict__ msg, const float* __restrict__ wsum,
    float* __restrict__ out, int mvox)
{
  __shared__ float G1[128 * 64];    // 32 KB, row-major: lane j reads col j
  __shared__ float WihT[64 * 192];  // 48 KB, [i][c]: lane-consecutive reads
  __shared__ float WhhT[64 * 192];  // 48 KB
  __shared__ float gb1[64], gw2[64];
  __shared__ float bih[192], bhh[192];
  __shared__ float gb2;

  int t = threadIdx.x;
  for (int s = t; s < 128 * 64; s += 1024) G1[s] = gate_w1[s];
  for (int s = t; s < 192 * 64; s += 1024) {
    int c = s >> 6, i = s & 63;           // src (192,64) row-major: W[c][i]
    WihT[i * 192 + c] = W_ih[s];          // dst [i][c]
    WhhT[i * 192 + c] = W_hh[s];
  }
  if (t < 64) { gb1[t] = gate_b1[t]; gw2[t] = gate_w2[t]; }
  if (t < 192) { bih[t] = b_ih[t]; bhh[t] = b_hh[t]; }
  if (t == 0) gb2 = gate_b2[0];
  __syncthreads();

  int lane = t & 63;
  int gwave = (blockIdx.x * 1024 + t) >> 6;
  int nwaves = (gridDim.x * 1024) >> 6;

  for (int m = gwave; m < mvox; m += nwaves) {
    float z = z_latent[(long)m * 64 + lane];
    float ws = wsum[m];
    float mg = msg[(long)m * 64 + lane] * (1.0f / (ws + 1e-6f));

    float u  = gb1[lane];
    float gr = bih[lane], gz = bih[64 + lane], gn = bih[128 + lane];
    float hr = bhh[lane], hz = bhh[64 + lane], hn = bhh[128 + lane];
#pragma unroll 8
    for (int i = 0; i < 64; ++i) {
      float zi = lane_bcast(z, i);
      float mi = lane_bcast(mg, i);
      u  = fmaf(zi, G1[i * 64 + lane], u);
      u  = fmaf(mi, G1[(64 + i) * 64 + lane], u);
      gr = fmaf(mi, WihT[i * 192 + lane], gr);
      gz = fmaf(mi, WihT[i * 192 + 64 + lane], gz);
      gn = fmaf(mi, WihT[i * 192 + 128 + lane], gn);
      hr = fmaf(zi, WhhT[i * 192 + lane], hr);
      hz = fmaf(zi, WhhT[i * 192 + 64 + lane], hz);
      hn = fmaf(zi, WhhT[i * 192 + 128 + lane], hn);
    }
    u = fmaxf(u, 0.0f);
    float gpre = wave_sum(u * gw2[lane]) + gb2;
    float gate = 1.0f / (1.0f + __expf(-gpre));

    float r   = 1.0f / (1.0f + __expf(-(gr + hr)));
    float zg  = 1.0f / (1.0f + __expf(-(gz + hz)));
    float nn_ = tanhf(gn + r * hn);
    float hnew = (1.0f - zg) * nn_ + zg * z;
    out[(long)m * 64 + lane] = z + gate * (hnew - z);
  }
}

extern "C" void kernel_launch(void* const* d_in, const int* in_sizes, int n_in,
                              void* d_out, int out_size, void* d_ws, size_t ws_size,
                              hipStream_t stream) {
  const float* f_pts   = (const float*)d_in[0];
  const float* pts     = (const float*)d_in[1];
  const float* z_lat   = (const float*)d_in[2];
  const float* centers = (const float*)d_in[3];
  const int*   cand    = (const int*)d_in[4];
  const float* sim_w1  = (const float*)d_in[5];
  const float* sim_b1  = (const float*)d_in[6];
  const float* sim_w2  = (const float*)d_in[7];
  // d_in[8] = sim_b2: uniform softmax shift, unused
  const float* gate_w1 = (const float*)d_in[9];
  const float* gate_b1 = (const float*)d_in[10];
  const float* gate_w2 = (const float*)d_in[11];
  const float* gate_b2 = (const float*)d_in[12];
  const float* W_ih    = (const float*)d_in[13];
  const float* W_hh    = (const float*)d_in[14];
  const float* b_ih    = (const float*)d_in[15];
  const float* b_hh    = (const float*)d_in[16];

  int N = in_sizes[0] / 64;
  int M = in_sizes[2] / 64;

  float* msg  = (float*)d_ws;                 // M*64 floats
  float* wsum = msg + (size_t)M * 64;         // M floats

  long zn = (long)M * 65;                     // divisible by 4
  zero_ws<<<2048, 256, 0, stream>>>((float*)d_ws, zn);

  stage1<<<2048, 256, 0, stream>>>(f_pts, pts, z_lat, centers, cand,
                                   sim_w1, sim_b1, sim_w2, msg, wsum, N);

  stage2<<<256, 1024, 0, stream>>>(z_lat, gate_w1, gate_b1, gate_w2, gate_b2,
                                   W_ih, W_hh, b_ih, b_hh, msg, wsum,
                                   (float*)d_out, M);
}

// Round 2
// 276.250 us; speedup vs baseline: 2.2311x; 2.2311x over previous
//
#include <hip/hip_runtime.h>
#include <math.h>

// LatentVoxelGrid: N=65536 pts, M=131072 voxels, K=8 cand, D=64.
// Stage 1: wave-per-point sim MLP (8-candidate-interleaved VALU) + softmax + atomic scatter.
// Stage 2: persistent bf16-MFMA kernel: [z|mg] @ [gate_w1 | W_ih^T | W_hh^T] fused with GRU.

typedef short bf16x8 __attribute__((ext_vector_type(8)));
typedef float f32x4 __attribute__((ext_vector_type(4)));
#define MFMA __builtin_amdgcn_mfma_f32_16x16x32_bf16

__device__ __forceinline__ float lane_bcast(float v, int i) {
  return __int_as_float(__builtin_amdgcn_readlane(__float_as_int(v), i));
}

__device__ __forceinline__ float wave_sum(float v) {
#pragma unroll
  for (int m = 32; m >= 1; m >>= 1) v += __shfl_xor(v, m, 64);
  return v;
}

__device__ __forceinline__ short f2bf(float f) {  // round-to-nearest-even
  unsigned u = __float_as_uint(f);
  unsigned r = (u + 0x7FFFu + ((u >> 16) & 1u)) >> 16;
  return (short)r;
}

__device__ __forceinline__ float sigm(float x) { return 1.0f / (1.0f + __expf(-x)); }

__global__ __launch_bounds__(256) void zero_ws(float* __restrict__ p, long n) {
  long i = (long)blockIdx.x * blockDim.x + threadIdx.x;
  long stride = (long)gridDim.x * blockDim.x;
  float4* p4 = (float4*)p;
  long n4 = n >> 2;
  for (long j = i; j < n4; j += stride) p4[j] = make_float4(0.f, 0.f, 0.f, 0.f);
}

// ---------------- Stage 1 ----------------
__global__ __launch_bounds__(256) void stage1(
    const float* __restrict__ f_pts, const float* __restrict__ pts,
    const float* __restrict__ z_latent, const float* __restrict__ centers,
    const int* __restrict__ cand_idx,
    const float* __restrict__ sim_w1, const float* __restrict__ sim_b1,
    const float* __restrict__ sim_w2,
    float* __restrict__ msg, float* __restrict__ wsum, int npts)
{
  __shared__ float W1s[131 * 64];  // row-major: lane j reads col j
  __shared__ float b1s[64];
  __shared__ float w2s[64];
  int t = threadIdx.x;
  for (int s = t; s < 131 * 64; s += 256) W1s[s] = sim_w1[s];
  if (t < 64) { b1s[t] = sim_b1[t]; w2s[t] = sim_w2[t]; }
  __syncthreads();

  int lane = t & 63;
  int gwave = (blockIdx.x * 256 + t) >> 6;
  int nwaves = (gridDim.x * 256) >> 6;

  for (int n = gwave; n < npts; n += nwaves) {
    float f = f_pts[n * 64 + lane];
    float p0 = pts[n * 3 + 0], p1 = pts[n * 3 + 1], p2 = pts[n * 3 + 2];

    // wave-uniform candidate indices via one lane-load + readlane -> SGPRs
    int ci8 = cand_idx[n * 8 + (lane & 7)];
    int c[8];
    float z[8];
#pragma unroll
    for (int k = 0; k < 8; ++k) {
      c[k] = __builtin_amdgcn_readlane(ci8, k);
      z[k] = z_latent[(long)c[k] * 64 + lane];
    }

    // candidate-invariant half: hb[j] = b1[j] + sum_i f[i] W1[i][j]  (2 chains)
    float hb0 = b1s[lane], hb1 = 0.f;
#pragma unroll 16
    for (int i = 0; i < 64; i += 2) {
      hb0 = fmaf(lane_bcast(f, i), W1s[i * 64 + lane], hb0);
      hb1 = fmaf(lane_bcast(f, i + 1), W1s[(i + 1) * 64 + lane], hb1);
    }
    float hb = hb0 + hb1;

    // init h[k] with delta part (centers loads are scalar: c[k] is SGPR)
    float h[8];
#pragma unroll
    for (int k = 0; k < 8; ++k) {
      float d0 = p0 - centers[c[k] * 3 + 0];
      float d1 = p1 - centers[c[k] * 3 + 1];
      float d2 = p2 - centers[c[k] * 3 + 2];
      float hh = fmaf(d0, W1s[128 * 64 + lane], hb);
      hh = fmaf(d1, W1s[129 * 64 + lane], hh);
      h[k] = fmaf(d2, W1s[130 * 64 + lane], hh);
    }

    // z half: 1 ds_read + 8 readlane + 8 independent FMAs per i
#pragma unroll 8
    for (int i = 0; i < 64; ++i) {
      float wcol = W1s[(64 + i) * 64 + lane];
#pragma unroll
      for (int k = 0; k < 8; ++k)
        h[k] = fmaf(lane_bcast(z[k], i), wcol, h[k]);
    }

    float sims[8];
#pragma unroll
    for (int k = 0; k < 8; ++k)
      sims[k] = wave_sum(fmaxf(h[k], 0.0f) * w2s[lane]);  // sim_b2 cancels in softmax

    // softmax over K=8, TAU=0.3
    float mx = sims[0];
#pragma unroll
    for (int k = 1; k < 8; ++k) mx = fmaxf(mx, sims[k]);
    float e[8], ssum = 0.f;
#pragma unroll
    for (int k = 0; k < 8; ++k) {
      e[k] = __expf((sims[k] - mx) * (1.0f / 0.3f));
      ssum += e[k];
    }
    float inv = 1.0f / ssum;
#pragma unroll
    for (int k = 0; k < 8; ++k) {
      float w = e[k] * inv;
      atomicAdd(&msg[(long)c[k] * 64 + lane], w * f);
      if (lane == 0) atomicAdd(&wsum[c[k]], w);
    }
  }
}

// ---------------- Stage 2 (bf16 MFMA) ----------------
// Per 128-row tile: A = [z | mg] (128x128 bf16). Outputs per row:
//   u (64) = relu(A @ gate_w1 + gb1)          -> gate = sig(sum(u*gw2)+gb2)
//   gi(192) = mg @ W_ih^T + b_ih ; gh(192) = z @ W_hh^T + b_hh -> GRU
#define AST 136  // Ab row stride (bf16): 272B, 16B-aligned, banks spread
#define GST 136  // G1t row stride
#define WST 88   // Wih/Whh row stride: 176B, 16B-aligned, banks spread

__global__ __launch_bounds__(512) void stage2(
    const float* __restrict__ z_latent,
    const float* __restrict__ gate_w1, const float* __restrict__ gate_b1,
    const float* __restrict__ gate_w2, const float* __restrict__ gate_b2,
    const float* __restrict__ W_ih, const float* __restrict__ W_hh,
    const float* __restrict__ b_ih, const float* __restrict__ b_hh,
    const float* __restrict__ msg, const float* __restrict__ wsum,
    float* __restrict__ out, int ntiles)
{
  __shared__ short Ab[128 * AST];    // [row][k]  k: 0-63 z, 64-127 mg
  __shared__ short G1t[64 * GST];    // [j][k] = gate_w1[k][j], K=128
  __shared__ short Wih_l[192 * WST]; // [j][k] = W_ih[j][k],  K=64
  __shared__ short Whh_l[192 * WST]; // [j][k] = W_hh[j][k],  K=64
  __shared__ float gb1s[64], gw2s[64], bihs[192], bhhs[192];
  __shared__ float gb2s;

  int t = threadIdx.x;
  for (int s = t; s < 64 * 128; s += 512) {       // gate_w1 (128,64) -> transpose
    int j = s & 63, k = s >> 6;
    G1t[j * GST + k] = f2bf(gate_w1[s]);
  }
  for (int s = t; s < 192 * 64; s += 512) {       // W_ih/W_hh (192,64) native
    int j = s >> 6, k = s & 63;
    Wih_l[j * WST + k] = f2bf(W_ih[s]);
    Whh_l[j * WST + k] = f2bf(W_hh[s]);
  }
  if (t < 64) { gb1s[t] = gate_b1[t]; gw2s[t] = gate_w2[t]; }
  if (t < 192) { bihs[t] = b_ih[t]; bhhs[t] = b_hh[t]; }
  if (t == 0) gb2s = gate_b2[0];
  __syncthreads();

  int wid = t >> 6, lane = t & 63;
  int lr = lane & 15, lg = lane >> 4;

  for (int tile = blockIdx.x; tile < ntiles; tile += gridDim.x) {
    int r0 = tile * 128;
    // ---- stage A tile: 512 threads = 128 rows x 4 segs of 16 cols ----
    {
      int row = t >> 2, seg = t & 3;
      const float4* zp = (const float4*)&z_latent[(long)(r0 + row) * 64 + seg * 16];
      const float4* mp = (const float4*)&msg[(long)(r0 + row) * 64 + seg * 16];
      float inv = 1.0f / (wsum[r0 + row] + 1e-6f);
      short* az = &Ab[row * AST + seg * 16];
      short* am = &Ab[row * AST + 64 + seg * 16];
#pragma unroll
      for (int q = 0; q < 4; ++q) {
        float4 zv = zp[q], mv = mp[q];
        az[q * 4 + 0] = f2bf(zv.x); az[q * 4 + 1] = f2bf(zv.y);
        az[q * 4 + 2] = f2bf(zv.z); az[q * 4 + 3] = f2bf(zv.w);
        am[q * 4 + 0] = f2bf(mv.x * inv); am[q * 4 + 1] = f2bf(mv.y * inv);
        am[q * 4 + 2] = f2bf(mv.z * inv); am[q * 4 + 3] = f2bf(mv.w * inv);
      }
    }
    __syncthreads();

    // ---- compute: wave wid owns rows [wid*16, wid*16+16) ----
    int rowbase = r0 + wid * 16;
    bf16x8 a[4];
#pragma unroll
    for (int kt = 0; kt < 4; ++kt)
      a[kt] = *(const bf16x8*)&Ab[(wid * 16 + lr) * AST + kt * 32 + lg * 8];

    f32x4 hnew[4], zs[4];
    f32x4 usum = {0.f, 0.f, 0.f, 0.f};

#pragma unroll
    for (int ct = 0; ct < 4; ++ct) {
      f32x4 au = {0,0,0,0}, air = {0,0,0,0}, aiz = {0,0,0,0}, ain = {0,0,0,0};
      f32x4 ahr = {0,0,0,0}, ahz = {0,0,0,0}, ahn = {0,0,0,0};
#pragma unroll
      for (int kt = 0; kt < 4; ++kt)
        au = MFMA(a[kt], *(const bf16x8*)&G1t[(ct * 16 + lr) * GST + kt * 32 + lg * 8], au, 0, 0, 0);
#pragma unroll
      for (int k2 = 0; k2 < 2; ++k2) {
        bf16x8 amg = a[2 + k2];  // mg half (k = 64..127)
        bf16x8 az_ = a[k2];      // z half  (k = 0..63)
        int ko = k2 * 32 + lg * 8;
        air = MFMA(amg, *(const bf16x8*)&Wih_l[(      ct * 16 + lr) * WST + ko], air, 0, 0, 0);
        aiz = MFMA(amg, *(const bf16x8*)&Wih_l[( 64 + ct * 16 + lr) * WST + ko], aiz, 0, 0, 0);
        ain = MFMA(amg, *(const bf16x8*)&Wih_l[(128 + ct * 16 + lr) * WST + ko], ain, 0, 0, 0);
        ahr = MFMA(az_, *(const bf16x8*)&Whh_l[(      ct * 16 + lr) * WST + ko], ahr, 0, 0, 0);
        ahz = MFMA(az_, *(const bf16x8*)&Whh_l[( 64 + ct * 16 + lr) * WST + ko], ahz, 0, 0, 0);
        ahn = MFMA(az_, *(const bf16x8*)&Whh_l[(128 + ct * 16 + lr) * WST + ko], ahn, 0, 0, 0);
      }
      int c = ct * 16 + lr;
#pragma unroll
      for (int e = 0; e < 4; ++e) {
        float zv = z_latent[(long)(rowbase + lg * 4 + e) * 64 + c];
        zs[ct][e] = zv;
        float uu = fmaxf(au[e] + gb1s[c], 0.0f);
        usum[e] += uu * gw2s[c];
        float rr = sigm(air[e] + bihs[c] + ahr[e] + bhhs[c]);
        float zg = sigm(aiz[e] + bihs[64 + c] + ahz[e] + bhhs[64 + c]);
        float nn = tanhf(ain[e] + bihs[128 + c] + rr * (ahn[e] + bhhs[128 + c]));
        hnew[ct][e] = (1.0f - zg) * nn + zg * zv;
      }
    }

    // gate: row-sum of u*gw2 across the 16 cols (lanes sharing lg)
#pragma unroll
    for (int m = 1; m <= 8; m <<= 1) {
#pragma unroll
      for (int e = 0; e < 4; ++e) {
        float v = usum[e];
        usum[e] = v + __shfl_xor(v, m, 64);
      }
    }
    float gate[4];
#pragma unroll
    for (int e = 0; e < 4; ++e) gate[e] = sigm(usum[e] + gb2s);

#pragma unroll
    for (int ct = 0; ct < 4; ++ct)
#pragma unroll
      for (int e = 0; e < 4; ++e)
        out[(long)(rowbase + lg * 4 + e) * 64 + ct * 16 + lr] =
            zs[ct][e] + gate[e] * (hnew[ct][e] - zs[ct][e]);
    __syncthreads();
  }
}

extern "C" void kernel_launch(void* const* d_in, const int* in_sizes, int n_in,
                              void* d_out, int out_size, void* d_ws, size_t ws_size,
                              hipStream_t stream) {
  const float* f_pts   = (const float*)d_in[0];
  const float* pts     = (const float*)d_in[1];
  const float* z_lat   = (const float*)d_in[2];
  const float* centers = (const float*)d_in[3];
  const int*   cand    = (const int*)d_in[4];
  const float* sim_w1  = (const float*)d_in[5];
  const float* sim_b1  = (const float*)d_in[6];
  const float* sim_w2  = (const float*)d_in[7];
  // d_in[8] = sim_b2: uniform softmax shift, unused
  const float* gate_w1 = (const float*)d_in[9];
  const float* gate_b1 = (const float*)d_in[10];
  const float* gate_w2 = (const float*)d_in[11];
  const float* gate_b2 = (const float*)d_in[12];
  const float* W_ih    = (const float*)d_in[13];
  const float* W_hh    = (const float*)d_in[14];
  const float* b_ih    = (const float*)d_in[15];
  const float* b_hh    = (const float*)d_in[16];

  int N = in_sizes[0] / 64;
  int M = in_sizes[2] / 64;

  float* msg  = (float*)d_ws;                 // M*64 floats
  float* wsum = msg + (size_t)M * 64;         // M floats

  long zn = (long)M * 65;                     // divisible by 4
  zero_ws<<<2048, 256, 0, stream>>>((float*)d_ws, zn);

  stage1<<<2048, 256, 0, stream>>>(f_pts, pts, z_lat, centers, cand,
                                   sim_w1, sim_b1, sim_w2, msg, wsum, N);

  int ntiles = M / 128;
  stage2<<<256, 512, 0, stream>>>(z_lat, gate_w1, gate_b1, gate_w2, gate_b2,
                                  W_ih, W_hh, b_ih, b_hh, msg, wsum,
                                  (float*)d_out, ntiles);
}

// Round 3
// 203.882 us; speedup vs baseline: 3.0230x; 1.3550x over previous
//
#include <hip/hip_runtime.h>
#include <math.h>

// LatentVoxelGrid: N=65536 pts, M=131072 voxels, K=8 cand, D=64.
// zero_ws -> prep (pack weight MFMA B-frags) -> hb (HB = f@W1f+b1, bf16)
// -> pair (MFMA sim MLP + softmax + atomic scatter) -> stage2 (gate+GRU MFMA).

typedef short bf16x8 __attribute__((ext_vector_type(8)));
typedef float f32x4 __attribute__((ext_vector_type(4)));
#define MFMA __builtin_amdgcn_mfma_f32_16x16x32_bf16

__device__ __forceinline__ float lane_bcast(float v, int i) {
  return __int_as_float(__builtin_amdgcn_readlane(__float_as_int(v), i));
}

__device__ __forceinline__ short f2bf(float f) {  // round-to-nearest-even
  unsigned u = __float_as_uint(f);
  unsigned r = (u + 0x7FFFu + ((u >> 16) & 1u)) >> 16;
  return (short)r;
}

__device__ __forceinline__ float bf2f(unsigned short h) {
  return __uint_as_float(((unsigned)h) << 16);
}

__device__ __forceinline__ float sigm(float x) { return 1.0f / (1.0f + __expf(-x)); }

__global__ __launch_bounds__(256) void zero_ws(float* __restrict__ p, long n) {
  long i = (long)blockIdx.x * blockDim.x + threadIdx.x;
  long stride = (long)gridDim.x * blockDim.x;
  float4* p4 = (float4*)p;
  long n4 = n >> 2;
  for (long j = i; j < n4; j += stride) p4[j] = make_float4(0.f, 0.f, 0.f, 0.f);
}

// Pack sim_w1 into per-lane MFMA B-fragments.
// bfZ: K=96 = [z(0..63) | delta(64..66) | zero(67..95)], cols 0..63. 12 frags (ct*3+kt).
// bfF: K=64 = f rows 0..63. 8 frags (ct*2+kt).
__global__ void prep_bfrags(const float* __restrict__ sim_w1,
                            short* __restrict__ bfZ, short* __restrict__ bfF) {
  int lane = threadIdx.x;  // 64 threads
  int lr = lane & 15, lg = lane >> 4;
#pragma unroll
  for (int ct = 0; ct < 4; ++ct)
#pragma unroll
    for (int kt = 0; kt < 3; ++kt) {
      bf16x8 b;
#pragma unroll
      for (int e = 0; e < 8; ++e) {
        int k = kt * 32 + lg * 8 + e;  // 0..95
        float v = (k < 67) ? sim_w1[(64 + k) * 64 + ct * 16 + lr] : 0.0f;
        b[e] = f2bf(v);
      }
      *(bf16x8*)&bfZ[(ct * 3 + kt) * 512 + lane * 8] = b;
    }
#pragma unroll
  for (int ct = 0; ct < 4; ++ct)
#pragma unroll
    for (int kt = 0; kt < 2; ++kt) {
      bf16x8 b;
#pragma unroll
      for (int e = 0; e < 8; ++e) {
        int k = kt * 32 + lg * 8 + e;  // 0..63
        b[e] = f2bf(sim_w1[k * 64 + ct * 16 + lr]);
      }
      *(bf16x8*)&bfF[(ct * 2 + kt) * 512 + lane * 8] = b;
    }
}

// HB[n][j] = (f_pts[n] @ W1f + b1)[j], stored bf16. One wave = 16 rows.
__global__ __launch_bounds__(256) void hb_kernel(
    const float* __restrict__ f_pts, const float* __restrict__ sim_b1,
    const short* __restrict__ bfF, unsigned short* __restrict__ HB, int npts)
{
  int wave = (blockIdx.x * 256 + threadIdx.x) >> 6;
  int lane = threadIdx.x & 63;
  int lr = lane & 15, lg = lane >> 4;
  int n0 = wave * 16;
  if (n0 >= npts) return;

  bf16x8 bf[8];
#pragma unroll
  for (int i = 0; i < 8; ++i) bf[i] = *(const bf16x8*)&bfF[i * 512 + lane * 8];

  bf16x8 a[2];
#pragma unroll
  for (int kt = 0; kt < 2; ++kt) {
    const float* src = &f_pts[(long)(n0 + lr) * 64 + kt * 32 + lg * 8];
    float4 v0 = *(const float4*)src;
    float4 v1 = *(const float4*)(src + 4);
    bf16x8 t;
    t[0] = f2bf(v0.x); t[1] = f2bf(v0.y); t[2] = f2bf(v0.z); t[3] = f2bf(v0.w);
    t[4] = f2bf(v1.x); t[5] = f2bf(v1.y); t[6] = f2bf(v1.z); t[7] = f2bf(v1.w);
    a[kt] = t;
  }

  f32x4 acc[4] = {{0,0,0,0},{0,0,0,0},{0,0,0,0},{0,0,0,0}};
#pragma unroll
  for (int ct = 0; ct < 4; ++ct) {
    acc[ct] = MFMA(a[0], bf[ct * 2 + 0], acc[ct], 0, 0, 0);
    acc[ct] = MFMA(a[1], bf[ct * 2 + 1], acc[ct], 0, 0, 0);
  }
#pragma unroll
  for (int ct = 0; ct < 4; ++ct) {
    float b1 = sim_b1[ct * 16 + lr];
#pragma unroll
    for (int e = 0; e < 4; ++e)
      HB[(long)(n0 + lg * 4 + e) * 64 + ct * 16 + lr] =
          (unsigned short)f2bf(acc[ct][e] + b1);
  }
}

// One wave-tile = 16 pairs = 2 points. TILES_PER_WAVE tiles per wave.
#define TILES_PER_WAVE 4
__global__ __launch_bounds__(256) void pair_kernel(
    const float* __restrict__ f_pts, const float* __restrict__ pts,
    const float* __restrict__ z_latent, const float* __restrict__ centers,
    const int* __restrict__ cand_idx, const float* __restrict__ sim_w2,
    const short* __restrict__ bfZ, const unsigned short* __restrict__ HB,
    float* __restrict__ msg, float* __restrict__ wsum)
{
  int wave = (blockIdx.x * 256 + threadIdx.x) >> 6;
  int lane = threadIdx.x & 63;
  int lr = lane & 15, lg = lane >> 4;

  bf16x8 b[12];
#pragma unroll
  for (int i = 0; i < 12; ++i) b[i] = *(const bf16x8*)&bfZ[i * 512 + lane * 8];
  float w2c[4];
#pragma unroll
  for (int ct = 0; ct < 4; ++ct) w2c[ct] = sim_w2[ct * 16 + lr];

#pragma unroll 1
  for (int t = 0; t < TILES_PER_WAVE; ++t) {
    int P = (wave * TILES_PER_WAVE + t) * 16;  // pair base
    int n0 = P >> 3;                            // 2 points per tile

    int c = cand_idx[P + lr];                   // candidate for row lr

    // A frags: kt=0,1 from gathered z row; kt=2 deltas (lg==0) else zero
    bf16x8 a[3];
#pragma unroll
    for (int kt = 0; kt < 2; ++kt) {
      const float* src = &z_latent[(long)c * 64 + kt * 32 + lg * 8];
      float4 v0 = *(const float4*)src;
      float4 v1 = *(const float4*)(src + 4);
      bf16x8 tt;
      tt[0] = f2bf(v0.x); tt[1] = f2bf(v0.y); tt[2] = f2bf(v0.z); tt[3] = f2bf(v0.w);
      tt[4] = f2bf(v1.x); tt[5] = f2bf(v1.y); tt[6] = f2bf(v1.z); tt[7] = f2bf(v1.w);
      a[kt] = tt;
    }
    {
      bf16x8 tt = {0, 0, 0, 0, 0, 0, 0, 0};
      if (lg == 0) {
        int n = n0 + (lr >> 3);
        tt[0] = f2bf(pts[n * 3 + 0] - centers[c * 3 + 0]);
        tt[1] = f2bf(pts[n * 3 + 1] - centers[c * 3 + 1]);
        tt[2] = f2bf(pts[n * 3 + 2] - centers[c * 3 + 2]);
      }
      a[2] = tt;
    }

    f32x4 acc[4] = {{0,0,0,0},{0,0,0,0},{0,0,0,0},{0,0,0,0}};
#pragma unroll
    for (int ct = 0; ct < 4; ++ct)
#pragma unroll
      for (int kt = 0; kt < 3; ++kt)
        acc[ct] = MFMA(a[kt], b[ct * 3 + kt], acc[ct], 0, 0, 0);

    // rows lg*4+e all belong to point n0 + (lg>>1)
    int nrow = n0 + (lg >> 1);
    f32x4 part = {0.f, 0.f, 0.f, 0.f};
#pragma unroll
    for (int ct = 0; ct < 4; ++ct) {
      float hbv = bf2f(HB[(long)nrow * 64 + ct * 16 + lr]);
#pragma unroll
      for (int e = 0; e < 4; ++e) {
        float u = fmaxf(acc[ct][e] + hbv, 0.0f);
        part[e] = fmaf(u, w2c[ct], part[e]);
      }
    }
    // reduce over the 16 lanes of the lg-group -> sims of rows lg*4+e
#pragma unroll
    for (int m = 1; m <= 8; m <<= 1)
#pragma unroll
      for (int e = 0; e < 4; ++e) part[e] += __shfl_xor(part[e], m, 64);

    // partner group (same point): lg0<->lg1, lg2<->lg3
    float other[4];
#pragma unroll
    for (int e = 0; e < 4; ++e) other[e] = __shfl_xor(part[e], 16, 64);

    float mx = part[0];
#pragma unroll
    for (int e = 1; e < 4; ++e) mx = fmaxf(mx, part[e]);
#pragma unroll
    for (int e = 0; e < 4; ++e) mx = fmaxf(mx, other[e]);
    float ex[4], se = 0.f, so = 0.f;
#pragma unroll
    for (int e = 0; e < 4; ++e) {
      ex[e] = __expf((part[e] - mx) * (1.0f / 0.3f));
      se += ex[e];
      so += __expf((other[e] - mx) * (1.0f / 0.3f));
    }
    float inv = 1.0f / (se + so);
    float w[4];
#pragma unroll
    for (int e = 0; e < 4; ++e) w[e] = ex[e] * inv;

    float fr0 = f_pts[(long)n0 * 64 + lane];
    float fr1 = f_pts[(long)(n0 + 1) * 64 + lane];

#pragma unroll
    for (int r = 0; r < 16; ++r) {
      float wv = lane_bcast(w[r & 3], (r >> 2) * 16);
      int cr = __builtin_amdgcn_readlane(c, r);
      float fv = (r < 8) ? fr0 : fr1;
      atomicAdd(&msg[(long)cr * 64 + lane], wv * fv);
      if (lane == r) atomicAdd(&wsum[cr], wv);
    }
  }
}

// ---------------- Stage 2 (bf16 MFMA gate+GRU) — unchanged from round 2 ------
#define AST 136
#define GST 136
#define WST 88

__global__ __launch_bounds__(512) void stage2(
    const float* __restrict__ z_latent,
    const float* __restrict__ gate_w1, const float* __restrict__ gate_b1,
    const float* __restrict__ gate_w2, const float* __restrict__ gate_b2,
    const float* __restrict__ W_ih, const float* __restrict__ W_hh,
    const float* __restrict__ b_ih, const float* __restrict__ b_hh,
    const float* __restrict__ msg, const float* __restrict__ wsum,
    float* __restrict__ out, int ntiles)
{
  __shared__ short Ab[128 * AST];
  __shared__ short G1t[64 * GST];
  __shared__ short Wih_l[192 * WST];
  __shared__ short Whh_l[192 * WST];
  __shared__ float gb1s[64], gw2s[64], bihs[192], bhhs[192];
  __shared__ float gb2s;

  int t = threadIdx.x;
  for (int s = t; s < 64 * 128; s += 512) {
    int j = s & 63, k = s >> 6;
    G1t[j * GST + k] = f2bf(gate_w1[s]);
  }
  for (int s = t; s < 192 * 64; s += 512) {
    int j = s >> 6, k = s & 63;
    Wih_l[j * WST + k] = f2bf(W_ih[s]);
    Whh_l[j * WST + k] = f2bf(W_hh[s]);
  }
  if (t < 64) { gb1s[t] = gate_b1[t]; gw2s[t] = gate_w2[t]; }
  if (t < 192) { bihs[t] = b_ih[t]; bhhs[t] = b_hh[t]; }
  if (t == 0) gb2s = gate_b2[0];
  __syncthreads();

  int wid = t >> 6, lane = t & 63;
  int lr = lane & 15, lg = lane >> 4;

  for (int tile = blockIdx.x; tile < ntiles; tile += gridDim.x) {
    int r0 = tile * 128;
    {
      int row = t >> 2, seg = t & 3;
      const float4* zp = (const float4*)&z_latent[(long)(r0 + row) * 64 + seg * 16];
      const float4* mp = (const float4*)&msg[(long)(r0 + row) * 64 + seg * 16];
      float inv = 1.0f / (wsum[r0 + row] + 1e-6f);
      short* az = &Ab[row * AST + seg * 16];
      short* am = &Ab[row * AST + 64 + seg * 16];
#pragma unroll
      for (int q = 0; q < 4; ++q) {
        float4 zv = zp[q], mv = mp[q];
        az[q * 4 + 0] = f2bf(zv.x); az[q * 4 + 1] = f2bf(zv.y);
        az[q * 4 + 2] = f2bf(zv.z); az[q * 4 + 3] = f2bf(zv.w);
        am[q * 4 + 0] = f2bf(mv.x * inv); am[q * 4 + 1] = f2bf(mv.y * inv);
        am[q * 4 + 2] = f2bf(mv.z * inv); am[q * 4 + 3] = f2bf(mv.w * inv);
      }
    }
    __syncthreads();

    int rowbase = r0 + wid * 16;
    bf16x8 a[4];
#pragma unroll
    for (int kt = 0; kt < 4; ++kt)
      a[kt] = *(const bf16x8*)&Ab[(wid * 16 + lr) * AST + kt * 32 + lg * 8];

    f32x4 hnew[4], zs[4];
    f32x4 usum = {0.f, 0.f, 0.f, 0.f};

#pragma unroll
    for (int ct = 0; ct < 4; ++ct) {
      f32x4 au = {0,0,0,0}, air = {0,0,0,0}, aiz = {0,0,0,0}, ain = {0,0,0,0};
      f32x4 ahr = {0,0,0,0}, ahz = {0,0,0,0}, ahn = {0,0,0,0};
#pragma unroll
      for (int kt = 0; kt < 4; ++kt)
        au = MFMA(a[kt], *(const bf16x8*)&G1t[(ct * 16 + lr) * GST + kt * 32 + lg * 8], au, 0, 0, 0);
#pragma unroll
      for (int k2 = 0; k2 < 2; ++k2) {
        bf16x8 amg = a[2 + k2];
        bf16x8 az_ = a[k2];
        int ko = k2 * 32 + lg * 8;
        air = MFMA(amg, *(const bf16x8*)&Wih_l[(      ct * 16 + lr) * WST + ko], air, 0, 0, 0);
        aiz = MFMA(amg, *(const bf16x8*)&Wih_l[( 64 + ct * 16 + lr) * WST + ko], aiz, 0, 0, 0);
        ain = MFMA(amg, *(const bf16x8*)&Wih_l[(128 + ct * 16 + lr) * WST + ko], ain, 0, 0, 0);
        ahr = MFMA(az_, *(const bf16x8*)&Whh_l[(      ct * 16 + lr) * WST + ko], ahr, 0, 0, 0);
        ahz = MFMA(az_, *(const bf16x8*)&Whh_l[( 64 + ct * 16 + lr) * WST + ko], ahz, 0, 0, 0);
        ahn = MFMA(az_, *(const bf16x8*)&Whh_l[(128 + ct * 16 + lr) * WST + ko], ahn, 0, 0, 0);
      }
      int c = ct * 16 + lr;
#pragma unroll
      for (int e = 0; e < 4; ++e) {
        float zv = z_latent[(long)(rowbase + lg * 4 + e) * 64 + c];
        zs[ct][e] = zv;
        float uu = fmaxf(au[e] + gb1s[c], 0.0f);
        usum[e] += uu * gw2s[c];
        float rr = sigm(air[e] + bihs[c] + ahr[e] + bhhs[c]);
        float zg = sigm(aiz[e] + bihs[64 + c] + ahz[e] + bhhs[64 + c]);
        float nn = tanhf(ain[e] + bihs[128 + c] + rr * (ahn[e] + bhhs[128 + c]));
        hnew[ct][e] = (1.0f - zg) * nn + zg * zv;
      }
    }

#pragma unroll
    for (int m = 1; m <= 8; m <<= 1)
#pragma unroll
      for (int e = 0; e < 4; ++e) {
        float v = usum[e];
        usum[e] = v + __shfl_xor(v, m, 64);
      }
    float gate[4];
#pragma unroll
    for (int e = 0; e < 4; ++e) gate[e] = sigm(usum[e] + gb2s);

#pragma unroll
    for (int ct = 0; ct < 4; ++ct)
#pragma unroll
      for (int e = 0; e < 4; ++e)
        out[(long)(rowbase + lg * 4 + e) * 64 + ct * 16 + lr] =
            zs[ct][e] + gate[e] * (hnew[ct][e] - zs[ct][e]);
    __syncthreads();
  }
}

extern "C" void kernel_launch(void* const* d_in, const int* in_sizes, int n_in,
                              void* d_out, int out_size, void* d_ws, size_t ws_size,
                              hipStream_t stream) {
  const float* f_pts   = (const float*)d_in[0];
  const float* pts     = (const float*)d_in[1];
  const float* z_lat   = (const float*)d_in[2];
  const float* centers = (const float*)d_in[3];
  const int*   cand    = (const int*)d_in[4];
  const float* sim_w1  = (const float*)d_in[5];
  const float* sim_b1  = (const float*)d_in[6];
  const float* sim_w2  = (const float*)d_in[7];
  // d_in[8] = sim_b2: uniform softmax shift, unused
  const float* gate_w1 = (const float*)d_in[9];
  const float* gate_b1 = (const float*)d_in[10];
  const float* gate_w2 = (const float*)d_in[11];
  const float* gate_b2 = (const float*)d_in[12];
  const float* W_ih    = (const float*)d_in[13];
  const float* W_hh    = (const float*)d_in[14];
  const float* b_ih    = (const float*)d_in[15];
  const float* b_hh    = (const float*)d_in[16];

  int N = in_sizes[0] / 64;
  int M = in_sizes[2] / 64;

  float* msg  = (float*)d_ws;                          // M*64 f32
  float* wsum = msg + (size_t)M * 64;                  // M f32
  unsigned short* HB = (unsigned short*)(wsum + M);    // N*64 bf16
  short* bfZ = (short*)(HB + (size_t)N * 64);          // 12*512 bf16
  short* bfF = bfZ + 12 * 512;                         // 8*512 bf16

  long zn = (long)M * 65;
  zero_ws<<<2048, 256, 0, stream>>>((float*)d_ws, zn);

  prep_bfrags<<<1, 64, 0, stream>>>(sim_w1, bfZ, bfF);

  hb_kernel<<<N / 16 / 4, 256, 0, stream>>>(f_pts, sim_b1, bfF, HB, N);

  int nwaves = (N * 8) / (16 * TILES_PER_WAVE);        // 8192 waves
  pair_kernel<<<nwaves / 4, 256, 0, stream>>>(f_pts, pts, z_lat, centers, cand,
                                              sim_w2, bfZ, HB, msg, wsum);

  int ntiles = M / 128;
  stage2<<<256, 512, 0, stream>>>(z_lat, gate_w1, gate_b1, gate_w2, gate_b2,
                                  W_ih, W_hh, b_ih, b_hh, msg, wsum,
                                  (float*)d_out, ntiles);
}

// Round 4
// 155.368 us; speedup vs baseline: 3.9669x; 1.3123x over previous
//
#include <hip/hip_runtime.h>
#include <math.h>

// LatentVoxelGrid: N=65536 pts, M=131072 voxels, K=8 cand, D=64.
// zero_ws -> prep (pack weight MFMA B-frags) -> to_bf16(z) -> hb (HB=f@W1f+b1)
// -> pair (MFMA sim MLP + softmax + pk_add_bf16 scatter) -> stage2 (gate+GRU MFMA).

typedef short bf16x8 __attribute__((ext_vector_type(8)));
typedef unsigned short u16x8 __attribute__((ext_vector_type(8)));
typedef float f32x4 __attribute__((ext_vector_type(4)));
#define MFMA __builtin_amdgcn_mfma_f32_16x16x32_bf16

__device__ __forceinline__ float lane_bcast(float v, int i) {
  return __int_as_float(__builtin_amdgcn_readlane(__float_as_int(v), i));
}

__device__ __forceinline__ short f2bf(float f) {  // round-to-nearest-even
  unsigned u = __float_as_uint(f);
  unsigned r = (u + 0x7FFFu + ((u >> 16) & 1u)) >> 16;
  return (short)r;
}

__device__ __forceinline__ float bf2f(unsigned short h) {
  return __uint_as_float(((unsigned)h) << 16);
}

__device__ __forceinline__ void pk_atomic_bf16(unsigned short* addr, unsigned val) {
  asm volatile("global_atomic_pk_add_bf16 %0, %1, off" :: "v"(addr), "v"(val) : "memory");
}

__device__ __forceinline__ float sigm(float x) { return 1.0f / (1.0f + __expf(-x)); }

__global__ __launch_bounds__(256) void zero_ws(float* __restrict__ p, long n) {
  long i = (long)blockIdx.x * blockDim.x + threadIdx.x;
  long stride = (long)gridDim.x * blockDim.x;
  float4* p4 = (float4*)p;
  long n4 = n >> 2;
  for (long j = i; j < n4; j += stride) p4[j] = make_float4(0.f, 0.f, 0.f, 0.f);
}

__global__ __launch_bounds__(256) void to_bf16(const float* __restrict__ src,
                                               unsigned short* __restrict__ dst, long n) {
  long i = ((long)blockIdx.x * 256 + threadIdx.x) * 8;
  long stride = (long)gridDim.x * 256 * 8;
  for (; i < n; i += stride) {
    float4 a = *(const float4*)&src[i];
    float4 b = *(const float4*)&src[i + 4];
    u16x8 o;
    o[0] = (unsigned short)f2bf(a.x); o[1] = (unsigned short)f2bf(a.y);
    o[2] = (unsigned short)f2bf(a.z); o[3] = (unsigned short)f2bf(a.w);
    o[4] = (unsigned short)f2bf(b.x); o[5] = (unsigned short)f2bf(b.y);
    o[6] = (unsigned short)f2bf(b.z); o[7] = (unsigned short)f2bf(b.w);
    *(u16x8*)&dst[i] = o;
  }
}

// Pack sim_w1 into per-lane MFMA B-fragments.
// bfZ: K=96 = [z(0..63) | delta(64..66) | zero(67..95)], cols 0..63. 12 frags.
// bfF: K=64 = f rows. 8 frags.
__global__ void prep_bfrags(const float* __restrict__ sim_w1,
                            short* __restrict__ bfZ, short* __restrict__ bfF) {
  int lane = threadIdx.x;  // 64 threads
  int lr = lane & 15, lg = lane >> 4;
#pragma unroll
  for (int ct = 0; ct < 4; ++ct)
#pragma unroll
    for (int kt = 0; kt < 3; ++kt) {
      bf16x8 b;
#pragma unroll
      for (int e = 0; e < 8; ++e) {
        int k = kt * 32 + lg * 8 + e;  // 0..95
        float v = (k < 67) ? sim_w1[(64 + k) * 64 + ct * 16 + lr] : 0.0f;
        b[e] = f2bf(v);
      }
      *(bf16x8*)&bfZ[(ct * 3 + kt) * 512 + lane * 8] = b;
    }
#pragma unroll
  for (int ct = 0; ct < 4; ++ct)
#pragma unroll
    for (int kt = 0; kt < 2; ++kt) {
      bf16x8 b;
#pragma unroll
      for (int e = 0; e < 8; ++e) {
        int k = kt * 32 + lg * 8 + e;  // 0..63
        b[e] = f2bf(sim_w1[k * 64 + ct * 16 + lr]);
      }
      *(bf16x8*)&bfF[(ct * 2 + kt) * 512 + lane * 8] = b;
    }
}

// HB[n][j] = (f_pts[n] @ W1f + b1)[j], stored bf16. One wave = 16 rows.
__global__ __launch_bounds__(256) void hb_kernel(
    const float* __restrict__ f_pts, const float* __restrict__ sim_b1,
    const short* __restrict__ bfF, unsigned short* __restrict__ HB, int npts)
{
  int wave = (blockIdx.x * 256 + threadIdx.x) >> 6;
  int lane = threadIdx.x & 63;
  int lr = lane & 15, lg = lane >> 4;
  int n0 = wave * 16;
  if (n0 >= npts) return;

  bf16x8 bf[8];
#pragma unroll
  for (int i = 0; i < 8; ++i) bf[i] = *(const bf16x8*)&bfF[i * 512 + lane * 8];

  bf16x8 a[2];
#pragma unroll
  for (int kt = 0; kt < 2; ++kt) {
    const float* src = &f_pts[(long)(n0 + lr) * 64 + kt * 32 + lg * 8];
    float4 v0 = *(const float4*)src;
    float4 v1 = *(const float4*)(src + 4);
    bf16x8 t;
    t[0] = f2bf(v0.x); t[1] = f2bf(v0.y); t[2] = f2bf(v0.z); t[3] = f2bf(v0.w);
    t[4] = f2bf(v1.x); t[5] = f2bf(v1.y); t[6] = f2bf(v1.z); t[7] = f2bf(v1.w);
    a[kt] = t;
  }

  f32x4 acc[4] = {{0,0,0,0},{0,0,0,0},{0,0,0,0},{0,0,0,0}};
#pragma unroll
  for (int ct = 0; ct < 4; ++ct) {
    acc[ct] = MFMA(a[0], bf[ct * 2 + 0], acc[ct], 0, 0, 0);
    acc[ct] = MFMA(a[1], bf[ct * 2 + 1], acc[ct], 0, 0, 0);
  }
#pragma unroll
  for (int ct = 0; ct < 4; ++ct) {
    float b1 = sim_b1[ct * 16 + lr];
#pragma unroll
    for (int e = 0; e < 4; ++e)
      HB[(long)(n0 + lg * 4 + e) * 64 + ct * 16 + lr] =
          (unsigned short)f2bf(acc[ct][e] + b1);
  }
}

// One wave-tile = 16 pairs = 2 points.
#define TILES_PER_WAVE 4
__global__ __launch_bounds__(256) void pair_kernel(
    const float* __restrict__ f_pts, const float* __restrict__ pts,
    const unsigned short* __restrict__ zbf, const float* __restrict__ centers,
    const int* __restrict__ cand_idx, const float* __restrict__ sim_w2,
    const short* __restrict__ bfZ, const unsigned short* __restrict__ HB,
    unsigned short* __restrict__ msg_bf, float* __restrict__ wsum)
{
  int wave = (blockIdx.x * 256 + threadIdx.x) >> 6;
  int lane = threadIdx.x & 63;
  int lr = lane & 15, lg = lane >> 4;
  int lh = lane & 31, half = lane >> 5;

  bf16x8 b[12];
#pragma unroll
  for (int i = 0; i < 12; ++i) b[i] = *(const bf16x8*)&bfZ[i * 512 + lane * 8];
  float w2c[4];
#pragma unroll
  for (int ct = 0; ct < 4; ++ct) w2c[ct] = sim_w2[ct * 16 + lr];

#pragma unroll 1
  for (int t = 0; t < TILES_PER_WAVE; ++t) {
    int P = (wave * TILES_PER_WAVE + t) * 16;  // pair base
    int n0 = P >> 3;                           // 2 points per tile

    int c = cand_idx[P + lr];                  // candidate for row lr

    // A frags: kt=0,1 from gathered bf16 z row; kt=2 deltas (lg==0) else zero
    bf16x8 a[3];
#pragma unroll
    for (int kt = 0; kt < 2; ++kt)
      a[kt] = *(const bf16x8*)&zbf[(long)c * 64 + kt * 32 + lg * 8];
    {
      bf16x8 tt = {0, 0, 0, 0, 0, 0, 0, 0};
      if (lg == 0) {
        int n = n0 + (lr >> 3);
        tt[0] = f2bf(pts[n * 3 + 0] - centers[c * 3 + 0]);
        tt[1] = f2bf(pts[n * 3 + 1] - centers[c * 3 + 1]);
        tt[2] = f2bf(pts[n * 3 + 2] - centers[c * 3 + 2]);
      }
      a[2] = tt;
    }

    f32x4 acc[4] = {{0,0,0,0},{0,0,0,0},{0,0,0,0},{0,0,0,0}};
#pragma unroll
    for (int ct = 0; ct < 4; ++ct)
#pragma unroll
      for (int kt = 0; kt < 3; ++kt)
        acc[ct] = MFMA(a[kt], b[ct * 3 + kt], acc[ct], 0, 0, 0);

    // rows lg*4+e belong to point n0 + (lg>>1)
    int nrow = n0 + (lg >> 1);
    f32x4 part = {0.f, 0.f, 0.f, 0.f};
#pragma unroll
    for (int ct = 0; ct < 4; ++ct) {
      float hbv = bf2f(HB[(long)nrow * 64 + ct * 16 + lr]);
#pragma unroll
      for (int e = 0; e < 4; ++e) {
        float u = fmaxf(acc[ct][e] + hbv, 0.0f);
        part[e] = fmaf(u, w2c[ct], part[e]);
      }
    }
#pragma unroll
    for (int m = 1; m <= 8; m <<= 1)
#pragma unroll
      for (int e = 0; e < 4; ++e) part[e] += __shfl_xor(part[e], m, 64);

    float other[4];
#pragma unroll
    for (int e = 0; e < 4; ++e) other[e] = __shfl_xor(part[e], 16, 64);

    float mx = part[0];
#pragma unroll
    for (int e = 1; e < 4; ++e) mx = fmaxf(mx, part[e]);
#pragma unroll
    for (int e = 0; e < 4; ++e) mx = fmaxf(mx, other[e]);
    float ex[4], se = 0.f, so = 0.f;
#pragma unroll
    for (int e = 0; e < 4; ++e) {
      ex[e] = __expf((part[e] - mx) * (1.0f / 0.3f));
      se += ex[e];
      so += __expf((other[e] - mx) * (1.0f / 0.3f));
    }
    float inv = 1.0f / (se + so);
    float w[4];
#pragma unroll
    for (int e = 0; e < 4; ++e) w[e] = ex[e] * inv;

    // wrow: lane r (0..15) gets w of MFMA row r (= w[r&3] from lane (r>>2)*16)
    int srcl = (lane >> 2) << 4;
    float t0 = __shfl(w[0], srcl, 64);
    float t1 = __shfl(w[1], srcl, 64);
    float t2 = __shfl(w[2], srcl, 64);
    float t3 = __shfl(w[3], srcl, 64);
    int esel = lane & 3;
    float wrow = esel == 0 ? t0 : esel == 1 ? t1 : esel == 2 ? t2 : t3;

    if (lane < 16) atomicAdd(&wsum[c], wrow);

    // scatter: iter i covers rows i (lanes 0-31, point n0) and i+8 (lanes 32-63, n0+1)
    int idx2 = 2 * lh;
    float2 fr0 = *(const float2*)&f_pts[(long)n0 * 64 + idx2];
    float2 fr1 = *(const float2*)&f_pts[(long)(n0 + 1) * 64 + idx2];
    float fx = half ? fr1.x : fr0.x;
    float fy = half ? fr1.y : fr0.y;

#pragma unroll
    for (int i = 0; i < 8; ++i) {
      float wA = lane_bcast(wrow, i);
      float wB = lane_bcast(wrow, i + 8);
      int cA = __builtin_amdgcn_readlane(c, i);
      int cB = __builtin_amdgcn_readlane(c, i + 8);
      float wv = half ? wB : wA;
      int cr = half ? cB : cA;
      unsigned lo = (unsigned)(unsigned short)f2bf(wv * fx);
      unsigned hi = (unsigned)(unsigned short)f2bf(wv * fy);
      pk_atomic_bf16(&msg_bf[(long)cr * 64 + idx2], lo | (hi << 16));
    }
  }
}

// ---------------- Stage 2 (bf16 MFMA gate+GRU) ----------------
#define AST 136
#define GST 136
#define WST 88

__global__ __launch_bounds__(512) void stage2(
    const float* __restrict__ z_latent,
    const float* __restrict__ gate_w1, const float* __restrict__ gate_b1,
    const float* __restrict__ gate_w2, const float* __restrict__ gate_b2,
    const float* __restrict__ W_ih, const float* __restrict__ W_hh,
    const float* __restrict__ b_ih, const float* __restrict__ b_hh,
    const unsigned short* __restrict__ msg_bf, const float* __restrict__ wsum,
    float* __restrict__ out, int ntiles)
{
  __shared__ short Ab[128 * AST];
  __shared__ short G1t[64 * GST];
  __shared__ short Wih_l[192 * WST];
  __shared__ short Whh_l[192 * WST];
  __shared__ float gb1s[64], gw2s[64], bihs[192], bhhs[192];
  __shared__ float gb2s;

  int t = threadIdx.x;
  for (int s = t; s < 64 * 128; s += 512) {
    int j = s & 63, k = s >> 6;
    G1t[j * GST + k] = f2bf(gate_w1[s]);
  }
  for (int s = t; s < 192 * 64; s += 512) {
    int j = s >> 6, k = s & 63;
    Wih_l[j * WST + k] = f2bf(W_ih[s]);
    Whh_l[j * WST + k] = f2bf(W_hh[s]);
  }
  if (t < 64) { gb1s[t] = gate_b1[t]; gw2s[t] = gate_w2[t]; }
  if (t < 192) { bihs[t] = b_ih[t]; bhhs[t] = b_hh[t]; }
  if (t == 0) gb2s = gate_b2[0];
  __syncthreads();

  int wid = t >> 6, lane = t & 63;
  int lr = lane & 15, lg = lane >> 4;

  for (int tile = blockIdx.x; tile < ntiles; tile += gridDim.x) {
    int r0 = tile * 128;
    {
      int row = t >> 2, seg = t & 3;
      const float4* zp = (const float4*)&z_latent[(long)(r0 + row) * 64 + seg * 16];
      const u16x8* mp = (const u16x8*)&msg_bf[(long)(r0 + row) * 64 + seg * 16];
      float inv = 1.0f / (wsum[r0 + row] + 1e-6f);
      short* az = &Ab[row * AST + seg * 16];
      short* am = &Ab[row * AST + 64 + seg * 16];
#pragma unroll
      for (int q = 0; q < 4; ++q) {
        float4 zv = zp[q];
        az[q * 4 + 0] = f2bf(zv.x); az[q * 4 + 1] = f2bf(zv.y);
        az[q * 4 + 2] = f2bf(zv.z); az[q * 4 + 3] = f2bf(zv.w);
      }
#pragma unroll
      for (int q = 0; q < 2; ++q) {
        u16x8 mv = mp[q];
#pragma unroll
        for (int e = 0; e < 8; ++e)
          am[q * 8 + e] = f2bf(bf2f(mv[e]) * inv);
      }
    }
    __syncthreads();

    int rowbase = r0 + wid * 16;
    bf16x8 a[4];
#pragma unroll
    for (int kt = 0; kt < 4; ++kt)
      a[kt] = *(const bf16x8*)&Ab[(wid * 16 + lr) * AST + kt * 32 + lg * 8];

    f32x4 hnew[4], zs[4];
    f32x4 usum = {0.f, 0.f, 0.f, 0.f};

#pragma unroll
    for (int ct = 0; ct < 4; ++ct) {
      f32x4 au = {0,0,0,0}, air = {0,0,0,0}, aiz = {0,0,0,0}, ain = {0,0,0,0};
      f32x4 ahr = {0,0,0,0}, ahz = {0,0,0,0}, ahn = {0,0,0,0};
#pragma unroll
      for (int kt = 0; kt < 4; ++kt)
        au = MFMA(a[kt], *(const bf16x8*)&G1t[(ct * 16 + lr) * GST + kt * 32 + lg * 8], au, 0, 0, 0);
#pragma unroll
      for (int k2 = 0; k2 < 2; ++k2) {
        bf16x8 amg = a[2 + k2];
        bf16x8 az_ = a[k2];
        int ko = k2 * 32 + lg * 8;
        air = MFMA(amg, *(const bf16x8*)&Wih_l[(      ct * 16 + lr) * WST + ko], air, 0, 0, 0);
        aiz = MFMA(amg, *(const bf16x8*)&Wih_l[( 64 + ct * 16 + lr) * WST + ko], aiz, 0, 0, 0);
        ain = MFMA(amg, *(const bf16x8*)&Wih_l[(128 + ct * 16 + lr) * WST + ko], ain, 0, 0, 0);
        ahr = MFMA(az_, *(const bf16x8*)&Whh_l[(      ct * 16 + lr) * WST + ko], ahr, 0, 0, 0);
        ahz = MFMA(az_, *(const bf16x8*)&Whh_l[( 64 + ct * 16 + lr) * WST + ko], ahz, 0, 0, 0);
        ahn = MFMA(az_, *(const bf16x8*)&Whh_l[(128 + ct * 16 + lr) * WST + ko], ahn, 0, 0, 0);
      }
      int c = ct * 16 + lr;
#pragma unroll
      for (int e = 0; e < 4; ++e) {
        float zv = z_latent[(long)(rowbase + lg * 4 + e) * 64 + c];
        zs[ct][e] = zv;
        float uu = fmaxf(au[e] + gb1s[c], 0.0f);
        usum[e] += uu * gw2s[c];
        float rr = sigm(air[e] + bihs[c] + ahr[e] + bhhs[c]);
        float zg = sigm(aiz[e] + bihs[64 + c] + ahz[e] + bhhs[64 + c]);
        float nn = tanhf(ain[e] + bihs[128 + c] + rr * (ahn[e] + bhhs[128 + c]));
        hnew[ct][e] = (1.0f - zg) * nn + zg * zv;
      }
    }

#pragma unroll
    for (int m = 1; m <= 8; m <<= 1)
#pragma unroll
      for (int e = 0; e < 4; ++e) {
        float v = usum[e];
        usum[e] = v + __shfl_xor(v, m, 64);
      }
    float gate[4];
#pragma unroll
    for (int e = 0; e < 4; ++e) gate[e] = sigm(usum[e] + gb2s);

#pragma unroll
    for (int ct = 0; ct < 4; ++ct)
#pragma unroll
      for (int e = 0; e < 4; ++e)
        out[(long)(rowbase + lg * 4 + e) * 64 + ct * 16 + lr] =
            zs[ct][e] + gate[e] * (hnew[ct][e] - zs[ct][e]);
    __syncthreads();
  }
}

extern "C" void kernel_launch(void* const* d_in, const int* in_sizes, int n_in,
                              void* d_out, int out_size, void* d_ws, size_t ws_size,
                              hipStream_t stream) {
  const float* f_pts   = (const float*)d_in[0];
  const float* pts     = (const float*)d_in[1];
  const float* z_lat   = (const float*)d_in[2];
  const float* centers = (const float*)d_in[3];
  const int*   cand    = (const int*)d_in[4];
  const float* sim_w1  = (const float*)d_in[5];
  const float* sim_b1  = (const float*)d_in[6];
  const float* sim_w2  = (const float*)d_in[7];
  // d_in[8] = sim_b2: uniform softmax shift, unused
  const float* gate_w1 = (const float*)d_in[9];
  const float* gate_b1 = (const float*)d_in[10];
  const float* gate_w2 = (const float*)d_in[11];
  const float* gate_b2 = (const float*)d_in[12];
  const float* W_ih    = (const float*)d_in[13];
  const float* W_hh    = (const float*)d_in[14];
  const float* b_ih    = (const float*)d_in[15];
  const float* b_hh    = (const float*)d_in[16];

  int N = in_sizes[0] / 64;
  int M = in_sizes[2] / 64;

  unsigned short* msg_bf = (unsigned short*)d_ws;        // M*64 bf16 (16.8 MB)
  float* wsum = (float*)(msg_bf + (size_t)M * 64);       // M f32 (0.5 MB)
  unsigned short* HB = (unsigned short*)(wsum + M);      // N*64 bf16 (8.4 MB)
  unsigned short* zbf = HB + (size_t)N * 64;             // M*64 bf16 (16.8 MB)
  short* bfZ = (short*)(zbf + (size_t)M * 64);           // 12*512 bf16
  short* bfF = bfZ + 12 * 512;                           // 8*512 bf16

  // zero msg_bf + wsum (contiguous): M*64*2 + M*4 bytes = M*33 floats
  zero_ws<<<2048, 256, 0, stream>>>((float*)d_ws, (long)M * 33);

  prep_bfrags<<<1, 64, 0, stream>>>(sim_w1, bfZ, bfF);

  to_bf16<<<1024, 256, 0, stream>>>(z_lat, zbf, (long)M * 64);

  hb_kernel<<<N / 16 / 4, 256, 0, stream>>>(f_pts, sim_b1, bfF, HB, N);

  int nwaves = (N * 8) / (16 * TILES_PER_WAVE);          // 8192 waves
  pair_kernel<<<nwaves / 4, 256, 0, stream>>>(f_pts, pts, zbf, centers, cand,
                                              sim_w2, bfZ, HB, msg_bf, wsum);

  int ntiles = M / 128;
  stage2<<<256, 512, 0, stream>>>(z_lat, gate_w1, gate_b1, gate_w2, gate_b2,
                                  W_ih, W_hh, b_ih, b_hh, msg_bf, wsum,
                                  (float*)d_out, ntiles);
}

// Round 5
// 113.598 us; speedup vs baseline: 5.4256x; 1.3677x over previous
//
#include <hip/hip_runtime.h>
#include <hip/hip_fp16.h>
#include <math.h>

// LatentVoxelGrid: N=65536 pts, M=131072 voxels, K=8 cand, D=64.
// convert (z,f->bf16, zero cursor, pack W1 MFMA frags)
// -> hb (HB = f@W1f+b1, MFMA)
// -> pair (MFMA sim MLP + softmax + bucket record write, CAP=32)
// -> gather (per-voxel Sum w*f / Sum w -> normalized bf16 msg)
// -> stage2 (gate MLP + GRU, bf16 MFMA).

typedef short bf16x8 __attribute__((ext_vector_type(8)));
typedef unsigned short u16x8 __attribute__((ext_vector_type(8)));
typedef float f32x4 __attribute__((ext_vector_type(4)));
#define MFMA __builtin_amdgcn_mfma_f32_16x16x32_bf16
#define CAP 32

__device__ __forceinline__ float lane_bcast(float v, int i) {
  return __int_as_float(__builtin_amdgcn_readlane(__float_as_int(v), i));
}

__device__ __forceinline__ short f2bf(float f) {  // round-to-nearest-even
  unsigned u = __float_as_uint(f);
  unsigned r = (u + 0x7FFFu + ((u >> 16) & 1u)) >> 16;
  return (short)r;
}

__device__ __forceinline__ float bf2f(unsigned short h) {
  return __uint_as_float(((unsigned)h) << 16);
}

__device__ __forceinline__ float sigm(float x) { return 1.0f / (1.0f + __expf(-x)); }

// ---- convert: zbf=bf16(z), fbf=bf16(f), cursor=0, pack W1 B-frags ----
__global__ __launch_bounds__(256) void convert_kernel(
    const float* __restrict__ z, const float* __restrict__ f,
    unsigned short* __restrict__ zbf, unsigned short* __restrict__ fbf,
    int* __restrict__ cursor, const float* __restrict__ sim_w1,
    short* __restrict__ bfZ, short* __restrict__ bfF, long nz, long nf, int M)
{
  long tid = (long)blockIdx.x * 256 + threadIdx.x;
  long nthr = (long)gridDim.x * 256;

  for (long i = tid; i < M; i += nthr) cursor[i] = 0;

  for (long i = tid * 8; i < nz; i += nthr * 8) {
    float4 a = *(const float4*)&z[i];
    float4 b = *(const float4*)&z[i + 4];
    u16x8 o;
    o[0] = (unsigned short)f2bf(a.x); o[1] = (unsigned short)f2bf(a.y);
    o[2] = (unsigned short)f2bf(a.z); o[3] = (unsigned short)f2bf(a.w);
    o[4] = (unsigned short)f2bf(b.x); o[5] = (unsigned short)f2bf(b.y);
    o[6] = (unsigned short)f2bf(b.z); o[7] = (unsigned short)f2bf(b.w);
    *(u16x8*)&zbf[i] = o;
  }
  for (long i = tid * 8; i < nf; i += nthr * 8) {
    float4 a = *(const float4*)&f[i];
    float4 b = *(const float4*)&f[i + 4];
    u16x8 o;
    o[0] = (unsigned short)f2bf(a.x); o[1] = (unsigned short)f2bf(a.y);
    o[2] = (unsigned short)f2bf(a.z); o[3] = (unsigned short)f2bf(a.w);
    o[4] = (unsigned short)f2bf(b.x); o[5] = (unsigned short)f2bf(b.y);
    o[6] = (unsigned short)f2bf(b.z); o[7] = (unsigned short)f2bf(b.w);
    *(u16x8*)&fbf[i] = o;
  }

  if (blockIdx.x == 0 && threadIdx.x < 64) {
    int lane = threadIdx.x;
    int lr = lane & 15, lg = lane >> 4;
#pragma unroll
    for (int ct = 0; ct < 4; ++ct)
#pragma unroll
      for (int kt = 0; kt < 3; ++kt) {
        bf16x8 b;
#pragma unroll
        for (int e = 0; e < 8; ++e) {
          int k = kt * 32 + lg * 8 + e;  // 0..95: [z(64) | delta(3) | pad]
          float v = (k < 67) ? sim_w1[(64 + k) * 64 + ct * 16 + lr] : 0.0f;
          b[e] = f2bf(v);
        }
        *(bf16x8*)&bfZ[(ct * 3 + kt) * 512 + lane * 8] = b;
      }
#pragma unroll
    for (int ct = 0; ct < 4; ++ct)
#pragma unroll
      for (int kt = 0; kt < 2; ++kt) {
        bf16x8 b;
#pragma unroll
        for (int e = 0; e < 8; ++e) {
          int k = kt * 32 + lg * 8 + e;  // 0..63
          b[e] = f2bf(sim_w1[k * 64 + ct * 16 + lr]);
        }
        *(bf16x8*)&bfF[(ct * 2 + kt) * 512 + lane * 8] = b;
      }
  }
}

// ---- hb: HB[n][j] = (f_pts[n] @ W1f + b1)[j], bf16. One wave = 16 rows ----
__global__ __launch_bounds__(256) void hb_kernel(
    const float* __restrict__ f_pts, const float* __restrict__ sim_b1,
    const short* __restrict__ bfF, unsigned short* __restrict__ HB, int npts)
{
  int wave = (blockIdx.x * 256 + threadIdx.x) >> 6;
  int lane = threadIdx.x & 63;
  int lr = lane & 15, lg = lane >> 4;
  int n0 = wave * 16;
  if (n0 >= npts) return;

  bf16x8 bf[8];
#pragma unroll
  for (int i = 0; i < 8; ++i) bf[i] = *(const bf16x8*)&bfF[i * 512 + lane * 8];

  bf16x8 a[2];
#pragma unroll
  for (int kt = 0; kt < 2; ++kt) {
    const float* src = &f_pts[(long)(n0 + lr) * 64 + kt * 32 + lg * 8];
    float4 v0 = *(const float4*)src;
    float4 v1 = *(const float4*)(src + 4);
    bf16x8 t;
    t[0] = f2bf(v0.x); t[1] = f2bf(v0.y); t[2] = f2bf(v0.z); t[3] = f2bf(v0.w);
    t[4] = f2bf(v1.x); t[5] = f2bf(v1.y); t[6] = f2bf(v1.z); t[7] = f2bf(v1.w);
    a[kt] = t;
  }

  f32x4 acc[4] = {{0,0,0,0},{0,0,0,0},{0,0,0,0},{0,0,0,0}};
#pragma unroll
  for (int ct = 0; ct < 4; ++ct) {
    acc[ct] = MFMA(a[0], bf[ct * 2 + 0], acc[ct], 0, 0, 0);
    acc[ct] = MFMA(a[1], bf[ct * 2 + 1], acc[ct], 0, 0, 0);
  }
#pragma unroll
  for (int ct = 0; ct < 4; ++ct) {
    float b1 = sim_b1[ct * 16 + lr];
#pragma unroll
    for (int e = 0; e < 4; ++e)
      HB[(long)(n0 + lg * 4 + e) * 64 + ct * 16 + lr] =
          (unsigned short)f2bf(acc[ct][e] + b1);
  }
}

// ---- pair: sim MLP + softmax + bucket record write ----
#define TILES_PER_WAVE 4
__global__ __launch_bounds__(256) void pair_kernel(
    const float* __restrict__ pts, const unsigned short* __restrict__ zbf,
    const float* __restrict__ centers, const int* __restrict__ cand_idx,
    const float* __restrict__ sim_w2, const short* __restrict__ bfZ,
    const unsigned short* __restrict__ HB,
    int* __restrict__ cursor, unsigned* __restrict__ rec)
{
  int wave = (blockIdx.x * 256 + threadIdx.x) >> 6;
  int lane = threadIdx.x & 63;
  int lr = lane & 15, lg = lane >> 4;

  bf16x8 b[12];
#pragma unroll
  for (int i = 0; i < 12; ++i) b[i] = *(const bf16x8*)&bfZ[i * 512 + lane * 8];
  float w2c[4];
#pragma unroll
  for (int ct = 0; ct < 4; ++ct) w2c[ct] = sim_w2[ct * 16 + lr];

#pragma unroll 1
  for (int t = 0; t < TILES_PER_WAVE; ++t) {
    int P = (wave * TILES_PER_WAVE + t) * 16;  // pair base
    int n0 = P >> 3;                           // 2 points per tile

    int c = cand_idx[P + lr];                  // candidate for row lr

    bf16x8 a[3];
#pragma unroll
    for (int kt = 0; kt < 2; ++kt)
      a[kt] = *(const bf16x8*)&zbf[(long)c * 64 + kt * 32 + lg * 8];
    {
      bf16x8 tt = {0, 0, 0, 0, 0, 0, 0, 0};
      if (lg == 0) {
        int n = n0 + (lr >> 3);
        tt[0] = f2bf(pts[n * 3 + 0] - centers[c * 3 + 0]);
        tt[1] = f2bf(pts[n * 3 + 1] - centers[c * 3 + 1]);
        tt[2] = f2bf(pts[n * 3 + 2] - centers[c * 3 + 2]);
      }
      a[2] = tt;
    }

    f32x4 acc[4] = {{0,0,0,0},{0,0,0,0},{0,0,0,0},{0,0,0,0}};
#pragma unroll
    for (int ct = 0; ct < 4; ++ct)
#pragma unroll
      for (int kt = 0; kt < 3; ++kt)
        acc[ct] = MFMA(a[kt], b[ct * 3 + kt], acc[ct], 0, 0, 0);

    // rows lg*4+e belong to point n0 + (lg>>1)
    int nrow = n0 + (lg >> 1);
    f32x4 part = {0.f, 0.f, 0.f, 0.f};
#pragma unroll
    for (int ct = 0; ct < 4; ++ct) {
      float hbv = bf2f(HB[(long)nrow * 64 + ct * 16 + lr]);
#pragma unroll
      for (int e = 0; e < 4; ++e) {
        float u = fmaxf(acc[ct][e] + hbv, 0.0f);
        part[e] = fmaf(u, w2c[ct], part[e]);
      }
    }
#pragma unroll
    for (int m = 1; m <= 8; m <<= 1)
#pragma unroll
      for (int e = 0; e < 4; ++e) part[e] += __shfl_xor(part[e], m, 64);

    float other[4];
#pragma unroll
    for (int e = 0; e < 4; ++e) other[e] = __shfl_xor(part[e], 16, 64);

    float mx = part[0];
#pragma unroll
    for (int e = 1; e < 4; ++e) mx = fmaxf(mx, part[e]);
#pragma unroll
    for (int e = 0; e < 4; ++e) mx = fmaxf(mx, other[e]);
    float ex[4], se = 0.f, so = 0.f;
#pragma unroll
    for (int e = 0; e < 4; ++e) {
      ex[e] = __expf((part[e] - mx) * (1.0f / 0.3f));
      se += ex[e];
      so += __expf((other[e] - mx) * (1.0f / 0.3f));
    }
    float inv = 1.0f / (se + so);
    float w[4];
#pragma unroll
    for (int e = 0; e < 4; ++e) w[e] = ex[e] * inv;

    // wrow: lane r (0..15) gets w of MFMA row r (= w[r&3] from lane (r>>2)*16)
    int srcl = (lane >> 2) << 4;
    float t0 = __shfl(w[0], srcl, 64);
    float t1 = __shfl(w[1], srcl, 64);
    float t2 = __shfl(w[2], srcl, 64);
    float t3 = __shfl(w[3], srcl, 64);
    int esel = lane & 3;
    float wrow = esel == 0 ? t0 : esel == 1 ? t1 : esel == 2 ? t2 : t3;

    if (lane < 16) {
      int slot = atomicAdd(&cursor[c], 1);
      if (slot < CAP) {
        int n_pt = n0 + (lane >> 3);
        unsigned short wh = __half_as_ushort(__float2half(wrow));
        rec[(long)c * CAP + slot] = ((unsigned)n_pt << 16) | (unsigned)wh;
      }
    }
  }
}

// ---- gather: msg[v] = (Sum w*f[n]) / (Sum w + eps), normalized bf16 ----
__global__ __launch_bounds__(256) void gather_kernel(
    const unsigned* __restrict__ rec, const int* __restrict__ cursor,
    const unsigned short* __restrict__ fbf, unsigned short* __restrict__ msg_bf,
    int mvox)
{
  int tid = blockIdx.x * 256 + threadIdx.x;
  int row = tid >> 2, seg = tid & 3;  // 4 threads per voxel, 16 cols each
  if (row >= mvox) return;

  int cnt = cursor[row];
  cnt = cnt < CAP ? cnt : CAP;
  const unsigned* rp = &rec[(long)row * CAP];

  float acc[16];
#pragma unroll
  for (int j = 0; j < 16; ++j) acc[j] = 0.f;
  float ws = 0.f;

  for (int i = 0; i < cnt; ++i) {
    unsigned r = rp[i];
    float w = __half2float(__ushort_as_half((unsigned short)(r & 0xffffu)));
    int n = r >> 16;
    ws += w;
    const u16x8* fp = (const u16x8*)&fbf[(long)n * 64 + seg * 16];
    u16x8 f0 = fp[0], f1 = fp[1];
#pragma unroll
    for (int j = 0; j < 8; ++j) {
      acc[j]     = fmaf(w, bf2f(f0[j]), acc[j]);
      acc[8 + j] = fmaf(w, bf2f(f1[j]), acc[8 + j]);
    }
  }
  float inv = 1.0f / (ws + 1e-6f);
  u16x8 o0, o1;
#pragma unroll
  for (int j = 0; j < 8; ++j) {
    o0[j] = (unsigned short)f2bf(acc[j] * inv);
    o1[j] = (unsigned short)f2bf(acc[8 + j] * inv);
  }
  *(u16x8*)&msg_bf[(long)row * 64 + seg * 16] = o0;
  *(u16x8*)&msg_bf[(long)row * 64 + seg * 16 + 8] = o1;
}

// ---------------- Stage 2 (bf16 MFMA gate+GRU) ----------------
#define AST 136
#define GST 136
#define WST 88

__global__ __launch_bounds__(512) void stage2(
    const float* __restrict__ z_latent,
    const float* __restrict__ gate_w1, const float* __restrict__ gate_b1,
    const float* __restrict__ gate_w2, const float* __restrict__ gate_b2,
    const float* __restrict__ W_ih, const float* __restrict__ W_hh,
    const float* __restrict__ b_ih, const float* __restrict__ b_hh,
    const unsigned short* __restrict__ msg_bf,
    float* __restrict__ out, int ntiles)
{
  __shared__ short Ab[128 * AST];
  __shared__ short G1t[64 * GST];
  __shared__ short Wih_l[192 * WST];
  __shared__ short Whh_l[192 * WST];
  __shared__ float gb1s[64], gw2s[64], bihs[192], bhhs[192];
  __shared__ float gb2s;

  int t = threadIdx.x;
  for (int s = t; s < 64 * 128; s += 512) {
    int j = s & 63, k = s >> 6;
    G1t[j * GST + k] = f2bf(gate_w1[s]);
  }
  for (int s = t; s < 192 * 64; s += 512) {
    int j = s >> 6, k = s & 63;
    Wih_l[j * WST + k] = f2bf(W_ih[s]);
    Whh_l[j * WST + k] = f2bf(W_hh[s]);
  }
  if (t < 64) { gb1s[t] = gate_b1[t]; gw2s[t] = gate_w2[t]; }
  if (t < 192) { bihs[t] = b_ih[t]; bhhs[t] = b_hh[t]; }
  if (t == 0) gb2s = gate_b2[0];
  __syncthreads();

  int wid = t >> 6, lane = t & 63;
  int lr = lane & 15, lg = lane >> 4;

  for (int tile = blockIdx.x; tile < ntiles; tile += gridDim.x) {
    int r0 = tile * 128;
    {
      int row = t >> 2, seg = t & 3;
      const float4* zp = (const float4*)&z_latent[(long)(r0 + row) * 64 + seg * 16];
      const u16x8* mp = (const u16x8*)&msg_bf[(long)(r0 + row) * 64 + seg * 16];
      short* az = &Ab[row * AST + seg * 16];
      short* am = &Ab[row * AST + 64 + seg * 16];
#pragma unroll
      for (int q = 0; q < 4; ++q) {
        float4 zv = zp[q];
        az[q * 4 + 0] = f2bf(zv.x); az[q * 4 + 1] = f2bf(zv.y);
        az[q * 4 + 2] = f2bf(zv.z); az[q * 4 + 3] = f2bf(zv.w);
      }
      *(u16x8*)&am[0] = mp[0];
      *(u16x8*)&am[8] = mp[1];
    }
    __syncthreads();

    int rowbase = r0 + wid * 16;
    bf16x8 a[4];
#pragma unroll
    for (int kt = 0; kt < 4; ++kt)
      a[kt] = *(const bf16x8*)&Ab[(wid * 16 + lr) * AST + kt * 32 + lg * 8];

    f32x4 hnew[4], zs[4];
    f32x4 usum = {0.f, 0.f, 0.f, 0.f};

#pragma unroll
    for (int ct = 0; ct < 4; ++ct) {
      f32x4 au = {0,0,0,0}, air = {0,0,0,0}, aiz = {0,0,0,0}, ain = {0,0,0,0};
      f32x4 ahr = {0,0,0,0}, ahz = {0,0,0,0}, ahn = {0,0,0,0};
#pragma unroll
      for (int kt = 0; kt < 4; ++kt)
        au = MFMA(a[kt], *(const bf16x8*)&G1t[(ct * 16 + lr) * GST + kt * 32 + lg * 8], au, 0, 0, 0);
#pragma unroll
      for (int k2 = 0; k2 < 2; ++k2) {
        bf16x8 amg = a[2 + k2];
        bf16x8 az_ = a[k2];
        int ko = k2 * 32 + lg * 8;
        air = MFMA(amg, *(const bf16x8*)&Wih_l[(      ct * 16 + lr) * WST + ko], air, 0, 0, 0);
        aiz = MFMA(amg, *(const bf16x8*)&Wih_l[( 64 + ct * 16 + lr) * WST + ko], aiz, 0, 0, 0);
        ain = MFMA(amg, *(const bf16x8*)&Wih_l[(128 + ct * 16 + lr) * WST + ko], ain, 0, 0, 0);
        ahr = MFMA(az_, *(const bf16x8*)&Whh_l[(      ct * 16 + lr) * WST + ko], ahr, 0, 0, 0);
        ahz = MFMA(az_, *(const bf16x8*)&Whh_l[( 64 + ct * 16 + lr) * WST + ko], ahz, 0, 0, 0);
        ahn = MFMA(az_, *(const bf16x8*)&Whh_l[(128 + ct * 16 + lr) * WST + ko], ahn, 0, 0, 0);
      }
      int c = ct * 16 + lr;
#pragma unroll
      for (int e = 0; e < 4; ++e) {
        float zv = z_latent[(long)(rowbase + lg * 4 + e) * 64 + c];
        zs[ct][e] = zv;
        float uu = fmaxf(au[e] + gb1s[c], 0.0f);
        usum[e] += uu * gw2s[c];
        float rr = sigm(air[e] + bihs[c] + ahr[e] + bhhs[c]);
        float zg = sigm(aiz[e] + bihs[64 + c] + ahz[e] + bhhs[64 + c]);
        float nn = tanhf(ain[e] + bihs[128 + c] + rr * (ahn[e] + bhhs[128 + c]));
        hnew[ct][e] = (1.0f - zg) * nn + zg * zv;
      }
    }

#pragma unroll
    for (int m = 1; m <= 8; m <<= 1)
#pragma unroll
      for (int e = 0; e < 4; ++e) {
        float v = usum[e];
        usum[e] = v + __shfl_xor(v, m, 64);
      }
    float gate[4];
#pragma unroll
    for (int e = 0; e < 4; ++e) gate[e] = sigm(usum[e] + gb2s);

#pragma unroll
    for (int ct = 0; ct < 4; ++ct)
#pragma unroll
      for (int e = 0; e < 4; ++e)
        out[(long)(rowbase + lg * 4 + e) * 64 + ct * 16 + lr] =
            zs[ct][e] + gate[e] * (hnew[ct][e] - zs[ct][e]);
    __syncthreads();
  }
}

extern "C" void kernel_launch(void* const* d_in, const int* in_sizes, int n_in,
                              void* d_out, int out_size, void* d_ws, size_t ws_size,
                              hipStream_t stream) {
  const float* f_pts   = (const float*)d_in[0];
  const float* pts     = (const float*)d_in[1];
  const float* z_lat   = (const float*)d_in[2];
  const float* centers = (const float*)d_in[3];
  const int*   cand    = (const int*)d_in[4];
  const float* sim_w1  = (const float*)d_in[5];
  const float* sim_b1  = (const float*)d_in[6];
  const float* sim_w2  = (const float*)d_in[7];
  // d_in[8] = sim_b2: uniform softmax shift, unused
  const float* gate_w1 = (const float*)d_in[9];
  const float* gate_b1 = (const float*)d_in[10];
  const float* gate_w2 = (const float*)d_in[11];
  const float* gate_b2 = (const float*)d_in[12];
  const float* W_ih    = (const float*)d_in[13];
  const float* W_hh    = (const float*)d_in[14];
  const float* b_ih    = (const float*)d_in[15];
  const float* b_hh    = (const float*)d_in[16];

  int N = in_sizes[0] / 64;
  int M = in_sizes[2] / 64;

  int* cursor = (int*)d_ws;                                   // M i32   (0.5 MB)
  unsigned* rec = (unsigned*)(cursor + M);                    // M*CAP u32 (16.8 MB)
  unsigned short* zbf = (unsigned short*)(rec + (size_t)M * CAP);  // M*64 bf16 (16.8 MB)
  unsigned short* msg_bf = zbf;                               // alias: zbf dead after pair
  unsigned short* fbf = zbf + (size_t)M * 64;                 // N*64 bf16 (8.4 MB)
  unsigned short* HB = fbf + (size_t)N * 64;                  // N*64 bf16 (8.4 MB)
  short* bfZ = (short*)(HB + (size_t)N * 64);                 // 12*512 bf16
  short* bfF = bfZ + 12 * 512;                                // 8*512 bf16

  convert_kernel<<<2048, 256, 0, stream>>>(z_lat, f_pts, zbf, fbf, cursor,
                                           sim_w1, bfZ, bfF,
                                           (long)M * 64, (long)N * 64, M);

  hb_kernel<<<N / 64, 256, 0, stream>>>(f_pts, sim_b1, bfF, HB, N);

  int nwaves = (N * 8) / (16 * TILES_PER_WAVE);               // 8192 waves
  pair_kernel<<<nwaves / 4, 256, 0, stream>>>(pts, zbf, centers, cand,
                                              sim_w2, bfZ, HB, cursor, rec);

  gather_kernel<<<(M * 4) / 256, 256, 0, stream>>>(rec, cursor, fbf, msg_bf, M);

  int ntiles = M / 128;
  stage2<<<256, 512, 0, stream>>>(z_lat, gate_w1, gate_b1, gate_w2, gate_b2,
                                  W_ih, W_hh, b_ih, b_hh, msg_bf,
                                  (float*)d_out, ntiles);
}

// Round 6
// 112.618 us; speedup vs baseline: 5.4728x; 1.0087x over previous
//
#include <hip/hip_runtime.h>
#include <hip/hip_fp16.h>
#include <math.h>

// LatentVoxelGrid: N=65536 pts, M=131072 voxels, K=8 cand, D=64.
// prep  (z->zbf, cursor=0, pack W1z frags; blocks<1024: HB=f@W1f+b1 MFMA + fbf write)
// pair  (MFMA sim MLP + softmax + bucket record write, depth-2 pipelined)
// gather(per-voxel Sum w*f / Sum w -> normalized bf16 msg)
// stage2(gate MLP + GRU, bf16 MFMA; z read once, epilogue z from LDS)

typedef short bf16x8 __attribute__((ext_vector_type(8)));
typedef unsigned short u16x8 __attribute__((ext_vector_type(8)));
typedef float f32x4 __attribute__((ext_vector_type(4)));
#define MFMA __builtin_amdgcn_mfma_f32_16x16x32_bf16
#define CAP 32

__device__ __forceinline__ float lane_bcast(float v, int i) {
  return __int_as_float(__builtin_amdgcn_readlane(__float_as_int(v), i));
}

__device__ __forceinline__ short f2bf(float f) {  // round-to-nearest-even
  unsigned u = __float_as_uint(f);
  unsigned r = (u + 0x7FFFu + ((u >> 16) & 1u)) >> 16;
  return (short)r;
}

__device__ __forceinline__ float bf2f(unsigned short h) {
  return __uint_as_float(((unsigned)h) << 16);
}

__device__ __forceinline__ float sigm(float x) { return 1.0f / (1.0f + __expf(-x)); }

// ---- prep: zbf, cursor=0, bfZ pack, HB + fbf (blocks < 1024) ----
__global__ __launch_bounds__(256) void prep_kernel(
    const float* __restrict__ z, const float* __restrict__ f,
    const float* __restrict__ sim_w1, const float* __restrict__ sim_b1,
    unsigned short* __restrict__ zbf, unsigned short* __restrict__ fbf,
    unsigned short* __restrict__ HB, int* __restrict__ cursor,
    short* __restrict__ bfZ, int M)
{
  long tid = (long)blockIdx.x * 256 + threadIdx.x;
  long nthr = (long)gridDim.x * 256;

  for (long i = tid; i < M; i += nthr) cursor[i] = 0;

  long nz = (long)M * 64;
  for (long i = tid * 8; i < nz; i += nthr * 8) {
    float4 a = *(const float4*)&z[i];
    float4 b4 = *(const float4*)&z[i + 4];
    u16x8 o;
    o[0] = (unsigned short)f2bf(a.x);  o[1] = (unsigned short)f2bf(a.y);
    o[2] = (unsigned short)f2bf(a.z);  o[3] = (unsigned short)f2bf(a.w);
    o[4] = (unsigned short)f2bf(b4.x); o[5] = (unsigned short)f2bf(b4.y);
    o[6] = (unsigned short)f2bf(b4.z); o[7] = (unsigned short)f2bf(b4.w);
    *(u16x8*)&zbf[i] = o;
  }

  if (blockIdx.x == gridDim.x - 1 && threadIdx.x < 64) {
    int lane = threadIdx.x;
    int lr = lane & 15, lg = lane >> 4;
#pragma unroll
    for (int ct = 0; ct < 4; ++ct)
#pragma unroll
      for (int kt = 0; kt < 3; ++kt) {
        bf16x8 b;
#pragma unroll
        for (int e = 0; e < 8; ++e) {
          int k = kt * 32 + lg * 8 + e;  // 0..95: [z(64) | delta(3) | pad]
          float v = (k < 67) ? sim_w1[(64 + k) * 64 + ct * 16 + lr] : 0.0f;
          b[e] = f2bf(v);
        }
        *(bf16x8*)&bfZ[(ct * 3 + kt) * 512 + lane * 8] = b;
      }
  }

  if (blockIdx.x < 1024) {  // hb: wave handles 16 point-rows; also writes fbf
    int wave = blockIdx.x * 4 + (threadIdx.x >> 6);
    int lane = threadIdx.x & 63;
    int lr = lane & 15, lg = lane >> 4;
    int n0 = wave * 16;

    bf16x8 bf[8];  // f-part B frags, loaded inline (sim_w1 is L2-hot)
#pragma unroll
    for (int ct = 0; ct < 4; ++ct)
#pragma unroll
      for (int kt = 0; kt < 2; ++kt) {
        bf16x8 bb;
#pragma unroll
        for (int e = 0; e < 8; ++e)
          bb[e] = f2bf(sim_w1[(kt * 32 + lg * 8 + e) * 64 + ct * 16 + lr]);
        bf[ct * 2 + kt] = bb;
      }

    bf16x8 a[2];
#pragma unroll
    for (int kt = 0; kt < 2; ++kt) {
      const float* src = &f[(long)(n0 + lr) * 64 + kt * 32 + lg * 8];
      float4 v0 = *(const float4*)src;
      float4 v1 = *(const float4*)(src + 4);
      bf16x8 t;
      t[0] = f2bf(v0.x); t[1] = f2bf(v0.y); t[2] = f2bf(v0.z); t[3] = f2bf(v0.w);
      t[4] = f2bf(v1.x); t[5] = f2bf(v1.y); t[6] = f2bf(v1.z); t[7] = f2bf(v1.w);
      a[kt] = t;
    }
    *(bf16x8*)&fbf[(long)(n0 + lr) * 64 + lg * 8] = a[0];
    *(bf16x8*)&fbf[(long)(n0 + lr) * 64 + 32 + lg * 8] = a[1];

    f32x4 acc[4] = {{0,0,0,0},{0,0,0,0},{0,0,0,0},{0,0,0,0}};
#pragma unroll
    for (int ct = 0; ct < 4; ++ct) {
      acc[ct] = MFMA(a[0], bf[ct * 2 + 0], acc[ct], 0, 0, 0);
      acc[ct] = MFMA(a[1], bf[ct * 2 + 1], acc[ct], 0, 0, 0);
    }
#pragma unroll
    for (int ct = 0; ct < 4; ++ct) {
      float b1 = sim_b1[ct * 16 + lr];
#pragma unroll
      for (int e = 0; e < 4; ++e)
        HB[(long)(n0 + lg * 4 + e) * 64 + ct * 16 + lr] =
            (unsigned short)f2bf(acc[ct][e] + b1);
    }
  }
}

// ---- pair: sim MLP + softmax + bucket record write (depth-2 pipeline) ----
#define TPW 4
__global__ __launch_bounds__(256) void pair_kernel(
    const float* __restrict__ pts, const unsigned short* __restrict__ zbf,
    const float* __restrict__ centers, const int* __restrict__ cand_idx,
    const float* __restrict__ sim_w2, const short* __restrict__ bfZ,
    const unsigned short* __restrict__ HB,
    int* __restrict__ cursor, unsigned* __restrict__ rec)
{
  int wave = (blockIdx.x * 256 + threadIdx.x) >> 6;
  int lane = threadIdx.x & 63;
  int lr = lane & 15, lg = lane >> 4;

  bf16x8 b[12];
#pragma unroll
  for (int i = 0; i < 12; ++i) b[i] = *(const bf16x8*)&bfZ[i * 512 + lane * 8];
  float w2c[4];
#pragma unroll
  for (int ct = 0; ct < 4; ++ct) w2c[ct] = sim_w2[ct * 16 + lr];

  int call = cand_idx[wave * 64 + lane];  // 4 tiles x 16 candidates, coalesced

  // prologue: tile 0 loads
  int c0 = __shfl(call, lr, 64);
  bf16x8 a0 = *(const bf16x8*)&zbf[(long)c0 * 64 + lg * 8];
  bf16x8 a1 = *(const bf16x8*)&zbf[(long)c0 * 64 + 32 + lg * 8];
  float cx = 0, cy = 0, cz = 0, px = 0, py = 0, pz = 0;
  if (lg == 0) {
    cx = centers[c0 * 3 + 0]; cy = centers[c0 * 3 + 1]; cz = centers[c0 * 3 + 2];
    int n = wave * TPW * 2 + (lr >> 3);
    px = pts[n * 3 + 0]; py = pts[n * 3 + 1]; pz = pts[n * 3 + 2];
  }

#pragma unroll
  for (int t = 0; t < TPW; ++t) {
    // prefetch tile t+1 while computing tile t
    int cn = c0; bf16x8 an0 = a0, an1 = a1;
    float cxn = 0, cyn = 0, czn = 0, pxn = 0, pyn = 0, pzn = 0;
    if (t + 1 < TPW) {
      cn = __shfl(call, (t + 1) * 16 + lr, 64);
      an0 = *(const bf16x8*)&zbf[(long)cn * 64 + lg * 8];
      an1 = *(const bf16x8*)&zbf[(long)cn * 64 + 32 + lg * 8];
      if (lg == 0) {
        cxn = centers[cn * 3 + 0]; cyn = centers[cn * 3 + 1]; czn = centers[cn * 3 + 2];
        int n = (wave * TPW + t + 1) * 2 + (lr >> 3);
        pxn = pts[n * 3 + 0]; pyn = pts[n * 3 + 1]; pzn = pts[n * 3 + 2];
      }
    }

    int n0 = (wave * TPW + t) * 2;

    bf16x8 ad = {0, 0, 0, 0, 0, 0, 0, 0};
    if (lg == 0) {
      ad[0] = f2bf(px - cx); ad[1] = f2bf(py - cy); ad[2] = f2bf(pz - cz);
    }

    f32x4 acc[4] = {{0,0,0,0},{0,0,0,0},{0,0,0,0},{0,0,0,0}};
#pragma unroll
    for (int ct = 0; ct < 4; ++ct) {
      acc[ct] = MFMA(a0, b[ct * 3 + 0], acc[ct], 0, 0, 0);
      acc[ct] = MFMA(a1, b[ct * 3 + 1], acc[ct], 0, 0, 0);
      acc[ct] = MFMA(ad, b[ct * 3 + 2], acc[ct], 0, 0, 0);
    }

    // rows lg*4+e belong to point n0 + (lg>>1)
    int nrow = n0 + (lg >> 1);
    f32x4 part = {0.f, 0.f, 0.f, 0.f};
#pragma unroll
    for (int ct = 0; ct < 4; ++ct) {
      float hbv = bf2f(HB[(long)nrow * 64 + ct * 16 + lr]);
#pragma unroll
      for (int e = 0; e < 4; ++e) {
        float u = fmaxf(acc[ct][e] + hbv, 0.0f);
        part[e] = fmaf(u, w2c[ct], part[e]);
      }
    }
#pragma unroll
    for (int m = 1; m <= 8; m <<= 1)
#pragma unroll
      for (int e = 0; e < 4; ++e) part[e] += __shfl_xor(part[e], m, 64);

    float other[4];
#pragma unroll
    for (int e = 0; e < 4; ++e) other[e] = __shfl_xor(part[e], 16, 64);

    float mx = part[0];
#pragma unroll
    for (int e = 1; e < 4; ++e) mx = fmaxf(mx, part[e]);
#pragma unroll
    for (int e = 0; e < 4; ++e) mx = fmaxf(mx, other[e]);
    float ex[4], se = 0.f, so = 0.f;
#pragma unroll
    for (int e = 0; e < 4; ++e) {
      ex[e] = __expf((part[e] - mx) * (1.0f / 0.3f));
      se += ex[e];
      so += __expf((other[e] - mx) * (1.0f / 0.3f));
    }
    float inv = 1.0f / (se + so);
    float w[4];
#pragma unroll
    for (int e = 0; e < 4; ++e) w[e] = ex[e] * inv;

    // wrow: lane r (0..15) gets w of MFMA row r (= w[r&3] from lane (r>>2)*16)
    int srcl = (lane >> 2) << 4;
    float t0 = __shfl(w[0], srcl, 64);
    float t1 = __shfl(w[1], srcl, 64);
    float t2 = __shfl(w[2], srcl, 64);
    float t3 = __shfl(w[3], srcl, 64);
    int esel = lane & 3;
    float wrow = esel == 0 ? t0 : esel == 1 ? t1 : esel == 2 ? t2 : t3;

    if (lane < 16) {
      int slot = atomicAdd(&cursor[c0], 1);
      if (slot < CAP) {
        int n_pt = n0 + (lane >> 3);
        unsigned short wh = __half_as_ushort(__float2half(wrow));
        rec[(long)c0 * CAP + slot] = ((unsigned)n_pt << 16) | (unsigned)wh;
      }
    }

    c0 = cn; a0 = an0; a1 = an1;
    cx = cxn; cy = cyn; cz = czn; px = pxn; py = pyn; pz = pzn;
  }
}

// ---- gather: msg[v] = (Sum w*f[n]) / (Sum w + eps), normalized bf16 ----
__global__ __launch_bounds__(256) void gather_kernel(
    const unsigned* __restrict__ rec, const int* __restrict__ cursor,
    const unsigned short* __restrict__ fbf, unsigned short* __restrict__ msg_bf,
    int mvox)
{
  int tid = blockIdx.x * 256 + threadIdx.x;
  int row = tid >> 2, seg = tid & 3;  // 4 threads per voxel, 16 cols each
  if (row >= mvox) return;

  int cnt = cursor[row];
  cnt = cnt < CAP ? cnt : CAP;
  const unsigned* rp = &rec[(long)row * CAP];

  float acc[16];
#pragma unroll
  for (int j = 0; j < 16; ++j) acc[j] = 0.f;
  float ws = 0.f;

  for (int i = 0; i < cnt; ++i) {
    unsigned r = rp[i];
    float w = __half2float(__ushort_as_half((unsigned short)(r & 0xffffu)));
    int n = r >> 16;
    ws += w;
    const u16x8* fp = (const u16x8*)&fbf[(long)n * 64 + seg * 16];
    u16x8 f0 = fp[0], f1 = fp[1];
#pragma unroll
    for (int j = 0; j < 8; ++j) {
      acc[j]     = fmaf(w, bf2f(f0[j]), acc[j]);
      acc[8 + j] = fmaf(w, bf2f(f1[j]), acc[8 + j]);
    }
  }
  float inv = 1.0f / (ws + 1e-6f);
  u16x8 o0, o1;
#pragma unroll
  for (int j = 0; j < 8; ++j) {
    o0[j] = (unsigned short)f2bf(acc[j] * inv);
    o1[j] = (unsigned short)f2bf(acc[8 + j] * inv);
  }
  *(u16x8*)&msg_bf[(long)row * 64 + seg * 16] = o0;
  *(u16x8*)&msg_bf[(long)row * 64 + seg * 16 + 8] = o1;
}

// ---------------- Stage 2 (bf16 MFMA gate+GRU) ----------------
#define AST 136
#define GST 136
#define WST 88

__global__ __launch_bounds__(512) void stage2(
    const float* __restrict__ z_latent,
    const float* __restrict__ gate_w1, const float* __restrict__ gate_b1,
    const float* __restrict__ gate_w2, const float* __restrict__ gate_b2,
    const float* __restrict__ W_ih, const float* __restrict__ W_hh,
    const float* __restrict__ b_ih, const float* __restrict__ b_hh,
    const unsigned short* __restrict__ msg_bf,
    float* __restrict__ out, int ntiles)
{
  __shared__ short Ab[128 * AST];
  __shared__ short G1t[64 * GST];
  __shared__ short Wih_l[192 * WST];
  __shared__ short Whh_l[192 * WST];
  __shared__ float gb1s[64], gw2s[64], bihs[192], bhhs[192];
  __shared__ float gb2s;

  int t = threadIdx.x;
  for (int s = t; s < 64 * 128; s += 512) {
    int j = s & 63, k = s >> 6;
    G1t[j * GST + k] = f2bf(gate_w1[s]);
  }
  for (int s = t; s < 192 * 64; s += 512) {
    int j = s >> 6, k = s & 63;
    Wih_l[j * WST + k] = f2bf(W_ih[s]);
    Whh_l[j * WST + k] = f2bf(W_hh[s]);
  }
  if (t < 64) { gb1s[t] = gate_b1[t]; gw2s[t] = gate_w2[t]; }
  if (t < 192) { bihs[t] = b_ih[t]; bhhs[t] = b_hh[t]; }
  if (t == 0) gb2s = gate_b2[0];
  __syncthreads();

  int wid = t >> 6, lane = t & 63;
  int lr = lane & 15, lg = lane >> 4;

  for (int tile = blockIdx.x; tile < ntiles; tile += gridDim.x) {
    int r0 = tile * 128;
    {
      int row = t >> 2, seg = t & 3;
      const float4* zp = (const float4*)&z_latent[(long)(r0 + row) * 64 + seg * 16];
      const u16x8* mp = (const u16x8*)&msg_bf[(long)(r0 + row) * 64 + seg * 16];
      short* az = &Ab[row * AST + seg * 16];
      short* am = &Ab[row * AST + 64 + seg * 16];
#pragma unroll
      for (int q = 0; q < 4; ++q) {
        float4 zv = zp[q];
        az[q * 4 + 0] = f2bf(zv.x); az[q * 4 + 1] = f2bf(zv.y);
        az[q * 4 + 2] = f2bf(zv.z); az[q * 4 + 3] = f2bf(zv.w);
      }
      *(u16x8*)&am[0] = mp[0];
      *(u16x8*)&am[8] = mp[1];
    }
    __syncthreads();

    int rowbase = r0 + wid * 16;
    bf16x8 a[4];
#pragma unroll
    for (int kt = 0; kt < 4; ++kt)
      a[kt] = *(const bf16x8*)&Ab[(wid * 16 + lr) * AST + kt * 32 + lg * 8];

    f32x4 hnew[4], zs[4];
    f32x4 usum = {0.f, 0.f, 0.f, 0.f};

#pragma unroll
    for (int ct = 0; ct < 4; ++ct) {
      f32x4 au = {0,0,0,0}, air = {0,0,0,0}, aiz = {0,0,0,0}, ain = {0,0,0,0};
      f32x4 ahr = {0,0,0,0}, ahz = {0,0,0,0}, ahn = {0,0,0,0};
#pragma unroll
      for (int kt = 0; kt < 4; ++kt)
        au = MFMA(a[kt], *(const bf16x8*)&G1t[(ct * 16 + lr) * GST + kt * 32 + lg * 8], au, 0, 0, 0);
#pragma unroll
      for (int k2 = 0; k2 < 2; ++k2) {
        bf16x8 amg = a[2 + k2];
        bf16x8 az_ = a[k2];
        int ko = k2 * 32 + lg * 8;
        air = MFMA(amg, *(const bf16x8*)&Wih_l[(      ct * 16 + lr) * WST + ko], air, 0, 0, 0);
        aiz = MFMA(amg, *(const bf16x8*)&Wih_l[( 64 + ct * 16 + lr) * WST + ko], aiz, 0, 0, 0);
        ain = MFMA(amg, *(const bf16x8*)&Wih_l[(128 + ct * 16 + lr) * WST + ko], ain, 0, 0, 0);
        ahr = MFMA(az_, *(const bf16x8*)&Whh_l[(      ct * 16 + lr) * WST + ko], ahr, 0, 0, 0);
        ahz = MFMA(az_, *(const bf16x8*)&Whh_l[( 64 + ct * 16 + lr) * WST + ko], ahz, 0, 0, 0);
        ahn = MFMA(az_, *(const bf16x8*)&Whh_l[(128 + ct * 16 + lr) * WST + ko], ahn, 0, 0, 0);
      }
      int c = ct * 16 + lr;
#pragma unroll
      for (int e = 0; e < 4; ++e) {
        // z from LDS (bf16) — saves the second global read of z_latent
        float zv = bf2f((unsigned short)Ab[(wid * 16 + lg * 4 + e) * AST + c]);
        zs[ct][e] = zv;
        float uu = fmaxf(au[e] + gb1s[c], 0.0f);
        usum[e] += uu * gw2s[c];
        float rr = sigm(air[e] + bihs[c] + ahr[e] + bhhs[c]);
        float zg = sigm(aiz[e] + bihs[64 + c] + ahz[e] + bhhs[64 + c]);
        float nn = tanhf(ain[e] + bihs[128 + c] + rr * (ahn[e] + bhhs[128 + c]));
        hnew[ct][e] = (1.0f - zg) * nn + zg * zv;
      }
    }

#pragma unroll
    for (int m = 1; m <= 8; m <<= 1)
#pragma unroll
      for (int e = 0; e < 4; ++e) {
        float v = usum[e];
        usum[e] = v + __shfl_xor(v, m, 64);
      }
    float gate[4];
#pragma unroll
    for (int e = 0; e < 4; ++e) gate[e] = sigm(usum[e] + gb2s);

#pragma unroll
    for (int ct = 0; ct < 4; ++ct)
#pragma unroll
      for (int e = 0; e < 4; ++e)
        out[(long)(rowbase + lg * 4 + e) * 64 + ct * 16 + lr] =
            zs[ct][e] + gate[e] * (hnew[ct][e] - zs[ct][e]);
    __syncthreads();
  }
}

extern "C" void kernel_launch(void* const* d_in, const int* in_sizes, int n_in,
                              void* d_out, int out_size, void* d_ws, size_t ws_size,
                              hipStream_t stream) {
  const float* f_pts   = (const float*)d_in[0];
  const float* pts     = (const float*)d_in[1];
  const float* z_lat   = (const float*)d_in[2];
  const float* centers = (const float*)d_in[3];
  const int*   cand    = (const int*)d_in[4];
  const float* sim_w1  = (const float*)d_in[5];
  const float* sim_b1  = (const float*)d_in[6];
  const float* sim_w2  = (const float*)d_in[7];
  // d_in[8] = sim_b2: uniform softmax shift, unused
  const float* gate_w1 = (const float*)d_in[9];
  const float* gate_b1 = (const float*)d_in[10];
  const float* gate_w2 = (const float*)d_in[11];
  const float* gate_b2 = (const float*)d_in[12];
  const float* W_ih    = (const float*)d_in[13];
  const float* W_hh    = (const float*)d_in[14];
  const float* b_ih    = (const float*)d_in[15];
  const float* b_hh    = (const float*)d_in[16];

  int N = in_sizes[0] / 64;
  int M = in_sizes[2] / 64;

  int* cursor = (int*)d_ws;                                        // M i32
  unsigned* rec = (unsigned*)(cursor + M);                         // M*CAP u32
  unsigned short* zbf = (unsigned short*)(rec + (size_t)M * CAP);  // M*64 bf16
  unsigned short* msg_bf = zbf;                                    // alias: zbf dead after pair
  unsigned short* fbf = zbf + (size_t)M * 64;                      // N*64 bf16
  unsigned short* HB = fbf + (size_t)N * 64;                       // N*64 bf16
  short* bfZ = (short*)(HB + (size_t)N * 64);                      // 12*512 bf16

  prep_kernel<<<2048, 256, 0, stream>>>(z_lat, f_pts, sim_w1, sim_b1,
                                        zbf, fbf, HB, cursor, bfZ, M);

  pair_kernel<<<2048, 256, 0, stream>>>(pts, zbf, centers, cand,
                                        sim_w2, bfZ, HB, cursor, rec);

  gather_kernel<<<(M * 4) / 256, 256, 0, stream>>>(rec, cursor, fbf, msg_bf, M);

  int ntiles = M / 128;
  stage2<<<256, 512, 0, stream>>>(z_lat, gate_w1, gate_b1, gate_w2, gate_b2,
                                  W_ih, W_hh, b_ih, b_hh, msg_bf,
                                  (float*)d_out, ntiles);
}

// Round 7
// 109.482 us; speedup vs baseline: 5.6296x; 1.0286x over previous
//
#include <hip/hip_runtime.h>
#include <hip/hip_fp16.h>
#include <math.h>

// LatentVoxelGrid: N=65536 pts, M=131072 voxels, K=8 cand, D=64.
// prep  (z->zbf, cursor=0, pack W1z frags; blocks<1024: HB=f@W1f+b1 MFMA + fbf write)
// pair  (MFMA sim MLP + softmax; cursor atomics hoisted to prologue, rec write epilogue)
// gather(per-voxel Sum w*f / Sum w -> normalized bf16 msg)
// stage2(gate MLP + GRU, bf16 MFMA; epilogue z via coalesced global read)

typedef short bf16x8 __attribute__((ext_vector_type(8)));
typedef unsigned short u16x8 __attribute__((ext_vector_type(8)));
typedef float f32x4 __attribute__((ext_vector_type(4)));
#define MFMA __builtin_amdgcn_mfma_f32_16x16x32_bf16
#define CAP 32

__device__ __forceinline__ short f2bf(float f) {  // round-to-nearest-even
  unsigned u = __float_as_uint(f);
  unsigned r = (u + 0x7FFFu + ((u >> 16) & 1u)) >> 16;
  return (short)r;
}

__device__ __forceinline__ float bf2f(unsigned short h) {
  return __uint_as_float(((unsigned)h) << 16);
}

__device__ __forceinline__ float sigm(float x) { return 1.0f / (1.0f + __expf(-x)); }

// ---- prep: zbf, cursor=0, bfZ pack, HB + fbf (blocks < 1024) ----
__global__ __launch_bounds__(256) void prep_kernel(
    const float* __restrict__ z, const float* __restrict__ f,
    const float* __restrict__ sim_w1, const float* __restrict__ sim_b1,
    unsigned short* __restrict__ zbf, unsigned short* __restrict__ fbf,
    unsigned short* __restrict__ HB, int* __restrict__ cursor,
    short* __restrict__ bfZ, int M)
{
  long tid = (long)blockIdx.x * 256 + threadIdx.x;
  long nthr = (long)gridDim.x * 256;

  for (long i = tid; i < M; i += nthr) cursor[i] = 0;

  long nz = (long)M * 64;
  for (long i = tid * 8; i < nz; i += nthr * 8) {
    float4 a = *(const float4*)&z[i];
    float4 b4 = *(const float4*)&z[i + 4];
    u16x8 o;
    o[0] = (unsigned short)f2bf(a.x);  o[1] = (unsigned short)f2bf(a.y);
    o[2] = (unsigned short)f2bf(a.z);  o[3] = (unsigned short)f2bf(a.w);
    o[4] = (unsigned short)f2bf(b4.x); o[5] = (unsigned short)f2bf(b4.y);
    o[6] = (unsigned short)f2bf(b4.z); o[7] = (unsigned short)f2bf(b4.w);
    *(u16x8*)&zbf[i] = o;
  }

  if (blockIdx.x == gridDim.x - 1 && threadIdx.x < 64) {
    int lane = threadIdx.x;
    int lr = lane & 15, lg = lane >> 4;
#pragma unroll
    for (int ct = 0; ct < 4; ++ct)
#pragma unroll
      for (int kt = 0; kt < 3; ++kt) {
        bf16x8 b;
#pragma unroll
        for (int e = 0; e < 8; ++e) {
          int k = kt * 32 + lg * 8 + e;  // 0..95: [z(64) | delta(3) | pad]
          float v = (k < 67) ? sim_w1[(64 + k) * 64 + ct * 16 + lr] : 0.0f;
          b[e] = f2bf(v);
        }
        *(bf16x8*)&bfZ[(ct * 3 + kt) * 512 + lane * 8] = b;
      }
  }

  if (blockIdx.x < 1024) {  // hb: wave handles 16 point-rows; also writes fbf
    int wave = blockIdx.x * 4 + (threadIdx.x >> 6);
    int lane = threadIdx.x & 63;
    int lr = lane & 15, lg = lane >> 4;
    int n0 = wave * 16;

    bf16x8 bf[8];  // f-part B frags (sim_w1 is L2-hot)
#pragma unroll
    for (int ct = 0; ct < 4; ++ct)
#pragma unroll
      for (int kt = 0; kt < 2; ++kt) {
        bf16x8 bb;
#pragma unroll
        for (int e = 0; e < 8; ++e)
          bb[e] = f2bf(sim_w1[(kt * 32 + lg * 8 + e) * 64 + ct * 16 + lr]);
        bf[ct * 2 + kt] = bb;
      }

    bf16x8 a[2];
#pragma unroll
    for (int kt = 0; kt < 2; ++kt) {
      const float* src = &f[(long)(n0 + lr) * 64 + kt * 32 + lg * 8];
      float4 v0 = *(const float4*)src;
      float4 v1 = *(const float4*)(src + 4);
      bf16x8 t;
      t[0] = f2bf(v0.x); t[1] = f2bf(v0.y); t[2] = f2bf(v0.z); t[3] = f2bf(v0.w);
      t[4] = f2bf(v1.x); t[5] = f2bf(v1.y); t[6] = f2bf(v1.z); t[7] = f2bf(v1.w);
      a[kt] = t;
    }
    *(bf16x8*)&fbf[(long)(n0 + lr) * 64 + lg * 8] = a[0];
    *(bf16x8*)&fbf[(long)(n0 + lr) * 64 + 32 + lg * 8] = a[1];

    f32x4 acc[4] = {{0,0,0,0},{0,0,0,0},{0,0,0,0},{0,0,0,0}};
#pragma unroll
    for (int ct = 0; ct < 4; ++ct) {
      acc[ct] = MFMA(a[0], bf[ct * 2 + 0], acc[ct], 0, 0, 0);
      acc[ct] = MFMA(a[1], bf[ct * 2 + 1], acc[ct], 0, 0, 0);
    }
#pragma unroll
    for (int ct = 0; ct < 4; ++ct) {
      float b1 = sim_b1[ct * 16 + lr];
#pragma unroll
      for (int e = 0; e < 4; ++e)
        HB[(long)(n0 + lg * 4 + e) * 64 + ct * 16 + lr] =
            (unsigned short)f2bf(acc[ct][e] + b1);
    }
  }
}

// ---- pair: sim MLP + softmax; atomics hoisted, rec write at end ----
#define TPW 4
__global__ __launch_bounds__(256) void pair_kernel(
    const float* __restrict__ pts, const unsigned short* __restrict__ zbf,
    const float* __restrict__ centers, const int* __restrict__ cand_idx,
    const float* __restrict__ sim_w2, const short* __restrict__ bfZ,
    const unsigned short* __restrict__ HB,
    int* __restrict__ cursor, unsigned* __restrict__ rec)
{
  int wave = (blockIdx.x * 256 + threadIdx.x) >> 6;
  int lane = threadIdx.x & 63;
  int lr = lane & 15, lg = lane >> 4;

  // this lane's own record: tile lane>>4, candidate row lane&15
  int call = cand_idx[wave * 64 + lane];           // coalesced
  int slot = atomicAdd(&cursor[call], 1);         // issued EARLY, hidden under compute

  bf16x8 b[12];
#pragma unroll
  for (int i = 0; i < 12; ++i) b[i] = *(const bf16x8*)&bfZ[i * 512 + lane * 8];
  float w2c[4];
#pragma unroll
  for (int ct = 0; ct < 4; ++ct) w2c[ct] = sim_w2[ct * 16 + lr];

  // prologue: tile 0 operand loads
  int c0 = __shfl(call, lr, 64);
  bf16x8 a0 = *(const bf16x8*)&zbf[(long)c0 * 64 + lg * 8];
  bf16x8 a1 = *(const bf16x8*)&zbf[(long)c0 * 64 + 32 + lg * 8];
  float cx = 0, cy = 0, cz = 0, px = 0, py = 0, pz = 0;
  if (lg == 0) {
    cx = centers[c0 * 3 + 0]; cy = centers[c0 * 3 + 1]; cz = centers[c0 * 3 + 2];
    int n = wave * TPW * 2 + (lr >> 3);
    px = pts[n * 3 + 0]; py = pts[n * 3 + 1]; pz = pts[n * 3 + 2];
  }
  float hb[4];
  {
    int nrow = wave * TPW * 2 + (lg >> 1);
#pragma unroll
    for (int ct = 0; ct < 4; ++ct)
      hb[ct] = bf2f(HB[(long)nrow * 64 + ct * 16 + lr]);
  }

  float wst[TPW];  // per-tile stashed weight (valid on lanes 0..15)

#pragma unroll
  for (int t = 0; t < TPW; ++t) {
    // prefetch tile t+1 while computing tile t
    int cn = c0; bf16x8 an0 = a0, an1 = a1;
    float cxn = 0, cyn = 0, czn = 0, pxn = 0, pyn = 0, pzn = 0;
    float hbn[4] = {0, 0, 0, 0};
    if (t + 1 < TPW) {
      cn = __shfl(call, (t + 1) * 16 + lr, 64);
      an0 = *(const bf16x8*)&zbf[(long)cn * 64 + lg * 8];
      an1 = *(const bf16x8*)&zbf[(long)cn * 64 + 32 + lg * 8];
      if (lg == 0) {
        cxn = centers[cn * 3 + 0]; cyn = centers[cn * 3 + 1]; czn = centers[cn * 3 + 2];
        int n = (wave * TPW + t + 1) * 2 + (lr >> 3);
        pxn = pts[n * 3 + 0]; pyn = pts[n * 3 + 1]; pzn = pts[n * 3 + 2];
      }
      int nrow = (wave * TPW + t + 1) * 2 + (lg >> 1);
#pragma unroll
      for (int ct = 0; ct < 4; ++ct)
        hbn[ct] = bf2f(HB[(long)nrow * 64 + ct * 16 + lr]);
    }

    bf16x8 ad = {0, 0, 0, 0, 0, 0, 0, 0};
    if (lg == 0) {
      ad[0] = f2bf(px - cx); ad[1] = f2bf(py - cy); ad[2] = f2bf(pz - cz);
    }

    f32x4 acc[4] = {{0,0,0,0},{0,0,0,0},{0,0,0,0},{0,0,0,0}};
#pragma unroll
    for (int ct = 0; ct < 4; ++ct) {
      acc[ct] = MFMA(a0, b[ct * 3 + 0], acc[ct], 0, 0, 0);
      acc[ct] = MFMA(a1, b[ct * 3 + 1], acc[ct], 0, 0, 0);
      acc[ct] = MFMA(ad, b[ct * 3 + 2], acc[ct], 0, 0, 0);
    }

    f32x4 part = {0.f, 0.f, 0.f, 0.f};
#pragma unroll
    for (int ct = 0; ct < 4; ++ct)
#pragma unroll
      for (int e = 0; e < 4; ++e) {
        float u = fmaxf(acc[ct][e] + hb[ct], 0.0f);
        part[e] = fmaf(u, w2c[ct], part[e]);
      }
#pragma unroll
    for (int m = 1; m <= 8; m <<= 1)
#pragma unroll
      for (int e = 0; e < 4; ++e) part[e] += __shfl_xor(part[e], m, 64);

    float other[4];
#pragma unroll
    for (int e = 0; e < 4; ++e) other[e] = __shfl_xor(part[e], 16, 64);

    float mx = part[0];
#pragma unroll
    for (int e = 1; e < 4; ++e) mx = fmaxf(mx, part[e]);
#pragma unroll
    for (int e = 0; e < 4; ++e) mx = fmaxf(mx, other[e]);
    float ex[4], se = 0.f, so = 0.f;
#pragma unroll
    for (int e = 0; e < 4; ++e) {
      ex[e] = __expf((part[e] - mx) * (1.0f / 0.3f));
      se += ex[e];
      so += __expf((other[e] - mx) * (1.0f / 0.3f));
    }
    float inv = 1.0f / (se + so);

    // wrow: lane r (0..15) = weight of MFMA row r  (= w[r&3] from lane (r>>2)*16)
    int srcl = (lane >> 2) << 4;
    float t0 = __shfl(ex[0] * inv, srcl, 64);
    float t1 = __shfl(ex[1] * inv, srcl, 64);
    float t2 = __shfl(ex[2] * inv, srcl, 64);
    float t3 = __shfl(ex[3] * inv, srcl, 64);
    int esel = lane & 3;
    wst[t] = esel == 0 ? t0 : esel == 1 ? t1 : esel == 2 ? t2 : t3;

    c0 = cn; a0 = an0; a1 = an1;
    cx = cxn; cy = cyn; cz = czn; px = pxn; py = pyn; pz = pzn;
#pragma unroll
    for (int ct = 0; ct < 4; ++ct) hb[ct] = hbn[ct];
  }

  // epilogue: route tile (lane>>4)'s weight for row (lane&15) to this lane
  float v0 = __shfl(wst[0], lr, 64);
  float v1 = __shfl(wst[1], lr, 64);
  float v2 = __shfl(wst[2], lr, 64);
  float v3 = __shfl(wst[3], lr, 64);
  float wv = lg == 0 ? v0 : lg == 1 ? v1 : lg == 2 ? v2 : v3;

  if (slot < CAP) {
    int n_pt = wave * 8 + 2 * lg + ((lane >> 3) & 1);
    unsigned short wh = __half_as_ushort(__float2half(wv));
    rec[(long)call * CAP + slot] = ((unsigned)n_pt << 16) | (unsigned)wh;
  }
}

// ---- gather: msg[v] = (Sum w*f[n]) / (Sum w + eps), normalized bf16 ----
__global__ __launch_bounds__(256) void gather_kernel(
    const unsigned* __restrict__ rec, const int* __restrict__ cursor,
    const unsigned short* __restrict__ fbf, unsigned short* __restrict__ msg_bf,
    int mvox)
{
  int tid = blockIdx.x * 256 + threadIdx.x;
  int row = tid >> 2, seg = tid & 3;  // 4 threads per voxel, 16 cols each
  if (row >= mvox) return;

  int cnt = cursor[row];
  cnt = cnt < CAP ? cnt : CAP;
  const unsigned* rp = &rec[(long)row * CAP];

  float acc[16];
#pragma unroll
  for (int j = 0; j < 16; ++j) acc[j] = 0.f;
  float ws = 0.f;

  for (int i = 0; i < cnt; ++i) {
    unsigned r = rp[i];
    float w = __half2float(__ushort_as_half((unsigned short)(r & 0xffffu)));
    int n = r >> 16;
    ws += w;
    const u16x8* fp = (const u16x8*)&fbf[(long)n * 64 + seg * 16];
    u16x8 f0 = fp[0], f1 = fp[1];
#pragma unroll
    for (int j = 0; j < 8; ++j) {
      acc[j]     = fmaf(w, bf2f(f0[j]), acc[j]);
      acc[8 + j] = fmaf(w, bf2f(f1[j]), acc[8 + j]);
    }
  }
  float inv = 1.0f / (ws + 1e-6f);
  u16x8 o0, o1;
#pragma unroll
  for (int j = 0; j < 8; ++j) {
    o0[j] = (unsigned short)f2bf(acc[j] * inv);
    o1[j] = (unsigned short)f2bf(acc[8 + j] * inv);
  }
  *(u16x8*)&msg_bf[(long)row * 64 + seg * 16] = o0;
  *(u16x8*)&msg_bf[(long)row * 64 + seg * 16 + 8] = o1;
}

// ---------------- Stage 2 (bf16 MFMA gate+GRU) ----------------
#define AST 136
#define GST 136
#define WST 88

__global__ __launch_bounds__(512) void stage2(
    const float* __restrict__ z_latent,
    const float* __restrict__ gate_w1, const float* __restrict__ gate_b1,
    const float* __restrict__ gate_w2, const float* __restrict__ gate_b2,
    const float* __restrict__ W_ih, const float* __restrict__ W_hh,
    const float* __restrict__ b_ih, const float* __restrict__ b_hh,
    const unsigned short* __restrict__ msg_bf,
    float* __restrict__ out, int ntiles)
{
  __shared__ short Ab[128 * AST];
  __shared__ short G1t[64 * GST];
  __shared__ short Wih_l[192 * WST];
  __shared__ short Whh_l[192 * WST];
  __shared__ float gb1s[64], gw2s[64], bihs[192], bhhs[192];
  __shared__ float gb2s;

  int t = threadIdx.x;
  for (int s = t; s < 64 * 128; s += 512) {
    int j = s & 63, k = s >> 6;
    G1t[j * GST + k] = f2bf(gate_w1[s]);
  }
  for (int s = t; s < 192 * 64; s += 512) {
    int j = s >> 6, k = s & 63;
    Wih_l[j * WST + k] = f2bf(W_ih[s]);
    Whh_l[j * WST + k] = f2bf(W_hh[s]);
  }
  if (t < 64) { gb1s[t] = gate_b1[t]; gw2s[t] = gate_w2[t]; }
  if (t < 192) { bihs[t] = b_ih[t]; bhhs[t] = b_hh[t]; }
  if (t == 0) gb2s = gate_b2[0];
  __syncthreads();

  int wid = t >> 6, lane = t & 63;
  int lr = lane & 15, lg = lane >> 4;

  for (int tile = blockIdx.x; tile < ntiles; tile += gridDim.x) {
    int r0 = tile * 128;
    {
      int row = t >> 2, seg = t & 3;
      const float4* zp = (const float4*)&z_latent[(long)(r0 + row) * 64 + seg * 16];
      const u16x8* mp = (const u16x8*)&msg_bf[(long)(r0 + row) * 64 + seg * 16];
      short* az = &Ab[row * AST + seg * 16];
      short* am = &Ab[row * AST + 64 + seg * 16];
#pragma unroll
      for (int q = 0; q < 4; ++q) {
        float4 zv = zp[q];
        az[q * 4 + 0] = f2bf(zv.x); az[q * 4 + 1] = f2bf(zv.y);
        az[q * 4 + 2] = f2bf(zv.z); az[q * 4 + 3] = f2bf(zv.w);
      }
      *(u16x8*)&am[0] = mp[0];
      *(u16x8*)&am[8] = mp[1];
    }
    __syncthreads();

    int rowbase = r0 + wid * 16;
    bf16x8 a[4];
#pragma unroll
    for (int kt = 0; kt < 4; ++kt)
      a[kt] = *(const bf16x8*)&Ab[(wid * 16 + lr) * AST + kt * 32 + lg * 8];

    f32x4 hnew[4], zs[4];
    f32x4 usum = {0.f, 0.f, 0.f, 0.f};

#pragma unroll
    for (int ct = 0; ct < 4; ++ct) {
      f32x4 au = {0,0,0,0}, air = {0,0,0,0}, aiz = {0,0,0,0}, ain = {0,0,0,0};
      f32x4 ahr = {0,0,0,0}, ahz = {0,0,0,0}, ahn = {0,0,0,0};
#pragma unroll
      for (int kt = 0; kt < 4; ++kt)
        au = MFMA(a[kt], *(const bf16x8*)&G1t[(ct * 16 + lr) * GST + kt * 32 + lg * 8], au, 0, 0, 0);
#pragma unroll
      for (int k2 = 0; k2 < 2; ++k2) {
        bf16x8 amg = a[2 + k2];
        bf16x8 az_ = a[k2];
        int ko = k2 * 32 + lg * 8;
        air = MFMA(amg, *(const bf16x8*)&Wih_l[(      ct * 16 + lr) * WST + ko], air, 0, 0, 0);
        aiz = MFMA(amg, *(const bf16x8*)&Wih_l[( 64 + ct * 16 + lr) * WST + ko], aiz, 0, 0, 0);
        ain = MFMA(amg, *(const bf16x8*)&Wih_l[(128 + ct * 16 + lr) * WST + ko], ain, 0, 0, 0);
        ahr = MFMA(az_, *(const bf16x8*)&Whh_l[(      ct * 16 + lr) * WST + ko], ahr, 0, 0, 0);
        ahz = MFMA(az_, *(const bf16x8*)&Whh_l[( 64 + ct * 16 + lr) * WST + ko], ahz, 0, 0, 0);
        ahn = MFMA(az_, *(const bf16x8*)&Whh_l[(128 + ct * 16 + lr) * WST + ko], ahn, 0, 0, 0);
      }
      int c = ct * 16 + lr;
#pragma unroll
      for (int e = 0; e < 4; ++e) {
        float zv = z_latent[(long)(rowbase + lg * 4 + e) * 64 + c];
        zs[ct][e] = zv;
        float uu = fmaxf(au[e] + gb1s[c], 0.0f);
        usum[e] += uu * gw2s[c];
        float rr = sigm(air[e] + bihs[c] + ahr[e] + bhhs[c]);
        float zg = sigm(aiz[e] + bihs[64 + c] + ahz[e] + bhhs[64 + c]);
        float nn = tanhf(ain[e] + bihs[128 + c] + rr * (ahn[e] + bhhs[128 + c]));
        hnew[ct][e] = (1.0f - zg) * nn + zg * zv;
      }
    }

#pragma unroll
    for (int m = 1; m <= 8; m <<= 1)
#pragma unroll
      for (int e = 0; e < 4; ++e) {
        float v = usum[e];
        usum[e] = v + __shfl_xor(v, m, 64);
      }
    float gate[4];
#pragma unroll
    for (int e = 0; e < 4; ++e) gate[e] = sigm(usum[e] + gb2s);

#pragma unroll
    for (int ct = 0; ct < 4; ++ct)
#pragma unroll
      for (int e = 0; e < 4; ++e)
        out[(long)(rowbase + lg * 4 + e) * 64 + ct * 16 + lr] =
            zs[ct][e] + gate[e] * (hnew[ct][e] - zs[ct][e]);
    __syncthreads();
  }
}

extern "C" void kernel_launch(void* const* d_in, const int* in_sizes, int n_in,
                              void* d_out, int out_size, void* d_ws, size_t ws_size,
                              hipStream_t stream) {
  const float* f_pts   = (const float*)d_in[0];
  const float* pts     = (const float*)d_in[1];
  const float* z_lat   = (const float*)d_in[2];
  const float* centers = (const float*)d_in[3];
  const int*   cand    = (const int*)d_in[4];
  const float* sim_w1  = (const float*)d_in[5];
  const float* sim_b1  = (const float*)d_in[6];
  const float* sim_w2  = (const float*)d_in[7];
  // d_in[8] = sim_b2: uniform softmax shift, unused
  const float* gate_w1 = (const float*)d_in[9];
  const float* gate_b1 = (const float*)d_in[10];
  const float* gate_w2 = (const float*)d_in[11];
  const float* gate_b2 = (const float*)d_in[12];
  const float* W_ih    = (const float*)d_in[13];
  const float* W_hh    = (const float*)d_in[14];
  const float* b_ih    = (const float*)d_in[15];
  const float* b_hh    = (const float*)d_in[16];

  int N = in_sizes[0] / 64;
  int M = in_sizes[2] / 64;

  int* cursor = (int*)d_ws;                                        // M i32
  unsigned* rec = (unsigned*)(cursor + M);                         // M*CAP u32
  unsigned short* zbf = (unsigned short*)(rec + (size_t)M * CAP);  // M*64 bf16
  unsigned short* msg_bf = zbf;                                    // alias: zbf dead after pair
  unsigned short* fbf = zbf + (size_t)M * 64;                      // N*64 bf16
  unsigned short* HB = fbf + (size_t)N * 64;                       // N*64 bf16
  short* bfZ = (short*)(HB + (size_t)N * 64);                      // 12*512 bf16

  prep_kernel<<<2048, 256, 0, stream>>>(z_lat, f_pts, sim_w1, sim_b1,
                                        zbf, fbf, HB, cursor, bfZ, M);

  pair_kernel<<<2048, 256, 0, stream>>>(pts, zbf, centers, cand,
                                        sim_w2, bfZ, HB, cursor, rec);

  gather_kernel<<<(M * 4) / 256, 256, 0, stream>>>(rec, cursor, fbf, msg_bf, M);

  int ntiles = M / 128;
  stage2<<<256, 512, 0, stream>>>(z_lat, gate_w1, gate_b1, gate_w2, gate_b2,
                                  W_ih, W_hh, b_ih, b_hh, msg_bf,
                                  (float*)d_out, ntiles);
}